// Round 12
// baseline (180.884 us; speedup 1.0000x reference)
//
#include <hip/hip_runtime.h>
#include <math.h>

#define BB 2
#define TT 2048
#define CC 1024
#define HH 16
#define DD 64
#define MM (BB*TT)
#define LCH 128
#define NCH (TT/LCH)
#define BHH (BB*HH)

#define OUT_OFF_KV   4194304
#define OUT_OFF_KSUM 4325376
#define MB 1048576

typedef unsigned int u32;
typedef unsigned short u16;
typedef __attribute__((ext_vector_type(8))) short s16x8;
typedef __attribute__((ext_vector_type(8))) unsigned short us8;
typedef __attribute__((ext_vector_type(4))) float f32x4;

__device__ __forceinline__ float fmap(float x) {
    return x > 0.0f ? x + 1.0f : expf(x);
}
__device__ __forceinline__ u16 bf16r(float f) {
    u32 u = __float_as_uint(f);
    u += 0x7fffu + ((u >> 16) & 1u);
    return (u16)(u >> 16);
}
__device__ __forceinline__ float bf2f(u16 u) {
    return __uint_as_float(((u32)u) << 16);
}
__device__ __forceinline__ void gload16(const void* g, void* l) {
    __builtin_amdgcn_global_load_lds(
        (const __attribute__((address_space(1))) u32*)g,
        (__attribute__((address_space(3))) u32*)l, 16, 0, 0);
}

// Fused fp32->bf16 cast: x then Wq,Wk,Wv,Wp into xbf and contiguous Wbf.
__global__ __launch_bounds__(256)
void f2bf_all(const float* __restrict__ x,
              const float* __restrict__ Wq, const float* __restrict__ Wk,
              const float* __restrict__ Wv, const float* __restrict__ Wp,
              u16* __restrict__ xbf, u16* __restrict__ wbf)
{
    const int i = blockIdx.x * 256 + threadIdx.x;   // 0 .. 1048575
    const float* src;
    u16* dst;
    int off;
    if (i < 524288) {
        src = x; dst = xbf; off = i;
    } else {
        const int j = i - 524288;
        const int sel = j >> 17;
        off = j & 131071;
        src = (sel == 0) ? Wq : (sel == 1) ? Wk : (sel == 2) ? Wv : Wp;
        dst = wbf + ((size_t)sel << 20);
    }
    const float4 a = ((const float4*)src)[off*2];
    const float4 b = ((const float4*)src)[off*2 + 1];
    us8 p;
    p[0]=bf16r(a.x); p[1]=bf16r(a.y); p[2]=bf16r(a.z); p[3]=bf16r(a.w);
    p[4]=bf16r(b.x); p[5]=bf16r(b.y); p[6]=bf16r(b.z); p[7]=bf16r(b.w);
    ((us8*)dst)[off] = p;
}

// ===== 8-phase helpers =====
__device__ __forceinline__ void read_a(const char* LB, int abase, int wm, int lr, int lg4,
                                       s16x8 (&af)[4][2])
{
    #pragma unroll
    for (int mi = 0; mi < 4; ++mi) {
        const int r = wm*64 + mi*16 + lr;
        #pragma unroll
        for (int ks = 0; ks < 2; ++ks) {
            const int gg = (ks*4 + lg4) ^ (r & 7);
            af[mi][ks] = *(const s16x8*)(LB + abase + r*128 + gg*16);
        }
    }
}
__device__ __forceinline__ void read_b(const char* LB, int bbase, int wn, int lr, int lg4,
                                       s16x8 (&bv)[2][2])
{
    #pragma unroll
    for (int ni = 0; ni < 2; ++ni) {
        const int r = wn*32 + ni*16 + lr;
        #pragma unroll
        for (int ks = 0; ks < 2; ++ks) {
            const int gg = (ks*4 + lg4) ^ (r & 7);
            bv[ni][ks] = *(const s16x8*)(LB + bbase + r*128 + gg*16);
        }
    }
}
__device__ __forceinline__ void phase_mfma(const s16x8 (&af)[4][2], const s16x8 (&bv)[2][2],
                                           f32x4 (&acc)[4][2])
{
    #pragma unroll
    for (int mi = 0; mi < 4; ++mi)
        #pragma unroll
        for (int ni = 0; ni < 2; ++ni)
            #pragma unroll
            for (int ks = 0; ks < 2; ++ks)
                acc[mi][ni] = __builtin_amdgcn_mfma_f32_16x16x32_bf16(
                    af[mi][ks], bv[ni][ks], acc[mi][ni], 0, 0, 0);
}

// ==================== 8-phase 256x256 QKV GEMM (read-ahead pipeline, R11) ====================
__global__ __launch_bounds__(512, 2)
void lca_gemm_qkv8(const u16* __restrict__ A, const u16* __restrict__ Wall,
                   u16* __restrict__ qp, u16* __restrict__ kp,
                   u16* __restrict__ kt, u16* __restrict__ vt)
{
    extern __shared__ char LB[];    // 131072 bytes
    const int tid  = threadIdx.x;
    const int lane = tid & 63;
    const int wid  = tid >> 6;      // 0..7
    const int wm   = wid >> 2;      // 0..1
    const int wn   = wid & 3;       // 0..3
    const int bm0  = blockIdx.y * 256;
    const int bn0g = blockIdx.x * 256;
    const int sel  = bn0g >> 10;    // 0,1,2
    const int nn0  = bn0g & (CC-1);
    const u16* W = Wall + ((size_t)sel << 20);
    const int NT = CC / 64;         // 16 K-tiles

    const int srow = (wid << 3) + (lane >> 3);   // 0..63 within sweep
    const int sg   = lane & 7;
    auto STAGE = [&](const u16* G, int ldsbase) {
        #pragma unroll
        for (int j = 0; j < 2; ++j) {
            const int r  = j*64 + srow;
            const int gs = sg ^ (r & 7);
            gload16(G + (size_t)r * CC + gs*8,
                    LB + ldsbase + (size_t)(j*64 + (wid<<3))*128);
        }
    };
    #define LDSA(slot,h) (((slot)*2 + (h))*16384)
    #define LDSB(slot,h) (65536 + ((slot)*2 + (h))*16384)

    f32x4 acc[4][4][2];
    #pragma unroll
    for (int q = 0; q < 4; ++q)
        #pragma unroll
        for (int mi = 0; mi < 4; ++mi)
            #pragma unroll
            for (int ni = 0; ni < 2; ++ni)
                acc[q][mi][ni] = (f32x4){0.f, 0.f, 0.f, 0.f};

    STAGE(A + (size_t)(bm0      ) * CC + 0,  LDSA(0,0));
    STAGE(A + (size_t)(bm0 + 128) * CC + 0,  LDSA(0,1));
    STAGE(W + (size_t)(nn0      ) * CC + 0,  LDSB(0,0));
    STAGE(W + (size_t)(nn0 + 128) * CC + 0,  LDSB(0,1));
    STAGE(A + (size_t)(bm0      ) * CC + 64, LDSA(1,0));
    STAGE(W + (size_t)(nn0      ) * CC + 64, LDSB(1,0));
    asm volatile("s_waitcnt vmcnt(4)" ::: "memory");
    __builtin_amdgcn_s_barrier();

    const int lr  = lane & 15;
    const int lg4 = lane >> 4;      // 0..3

    s16x8 afr0[4][2], afr1[4][2], b0r[2][2], b1r[2][2];
    read_a(LB, LDSA(0,0), wm, lr, lg4, afr0);
    read_b(LB, LDSB(0,0), wn, lr, lg4, b0r);

    for (int t = 0; t < NT; ++t) {
        const int slot  = t & 1;
        const int nslot = slot ^ 1;

        // q0: stage A1(t+1); read b1=B1(t); MFMA(afr0,b0r)
        if (t+1 < NT) STAGE(A + (size_t)(bm0 + 128)*CC + (t+1)*64, LDSA(nslot,1));
        read_b(LB, LDSB(slot,1), wn, lr, lg4, b1r);
        __builtin_amdgcn_sched_barrier(0);
        if (t < NT-1) asm volatile("s_waitcnt vmcnt(6)" ::: "memory");
        asm volatile("s_waitcnt lgkmcnt(4)" ::: "memory");
        __builtin_amdgcn_sched_barrier(0);
        __builtin_amdgcn_s_setprio(1);
        phase_mfma(afr0, b0r, acc[0]);
        __builtin_amdgcn_s_setprio(0);
        __builtin_amdgcn_sched_barrier(0);
        __builtin_amdgcn_s_barrier();

        // q1: stage B1(t+1); read afr1=A1(t); MFMA(afr0,b1r)
        if (t+1 < NT) STAGE(W + (size_t)(nn0 + 128)*CC + (t+1)*64, LDSB(nslot,1));
        read_a(LB, LDSA(slot,1), wm, lr, lg4, afr1);
        __builtin_amdgcn_sched_barrier(0);
        if (t < NT-1) asm volatile("s_waitcnt vmcnt(6)" ::: "memory");
        asm volatile("s_waitcnt lgkmcnt(8)" ::: "memory");
        __builtin_amdgcn_sched_barrier(0);
        __builtin_amdgcn_s_setprio(1);
        phase_mfma(afr0, b1r, acc[1]);
        __builtin_amdgcn_s_setprio(0);
        __builtin_amdgcn_sched_barrier(0);
        __builtin_amdgcn_s_barrier();

        // q2: stage A0(t+2); no reads; MFMA(afr1,b0r)
        if (t+2 < NT) STAGE(A + (size_t)(bm0)*CC + (t+2)*64, LDSA(slot,0));
        __builtin_amdgcn_sched_barrier(0);
        if (t < NT-1) asm volatile("s_waitcnt vmcnt(4)" ::: "memory");
        asm volatile("s_waitcnt lgkmcnt(0)" ::: "memory");
        __builtin_amdgcn_sched_barrier(0);
        __builtin_amdgcn_s_setprio(1);
        phase_mfma(afr1, b0r, acc[2]);
        __builtin_amdgcn_s_setprio(0);
        __builtin_amdgcn_sched_barrier(0);
        __builtin_amdgcn_s_barrier();

        // q3: stage B0(t+2); read afr0=A0(t+1), b0r=B0(t+1); MFMA(afr1,b1r)
        if (t+2 < NT) STAGE(W + (size_t)(nn0)*CC + (t+2)*64, LDSB(slot,0));
        if (t+1 < NT) {
            read_a(LB, LDSA(nslot,0), wm, lr, lg4, afr0);
            read_b(LB, LDSB(nslot,0), wn, lr, lg4, b0r);
        }
        __builtin_amdgcn_sched_barrier(0);
        if (t < NT-2)       asm volatile("s_waitcnt vmcnt(4)" ::: "memory");
        else if (t == NT-2) asm volatile("s_waitcnt vmcnt(0)" ::: "memory");
        __builtin_amdgcn_sched_barrier(0);
        __builtin_amdgcn_s_setprio(1);
        phase_mfma(afr1, b1r, acc[3]);
        __builtin_amdgcn_s_setprio(0);
        __builtin_amdgcn_sched_barrier(0);
        __builtin_amdgcn_s_barrier();
    }

    // epilogue: scalar stores (proven, incl. nn0 fix)
    #pragma unroll
    for (int q = 0; q < 4; ++q) {
        const int mh = q >> 1, nh = q & 1;
        #pragma unroll
        for (int mi = 0; mi < 4; ++mi) {
            #pragma unroll
            for (int ni = 0; ni < 2; ++ni) {
                const int coln = nn0 + nh*128 + wn*32 + ni*16 + lr;
                const int rb   = bm0 + mh*128 + wm*64 + mi*16 + lg4*4;
                const int h = coln >> 6, d = coln & (DD-1);
                const int b = rb >> 11, t0 = rb & (TT-1);
                u16 bvv[4];
                #pragma unroll
                for (int r = 0; r < 4; ++r) {
                    float val = acc[q][mi][ni][r];
                    if (sel != 2) val = fmap(val);
                    bvv[r] = bf16r(val);
                }
                if (sel == 0) {
                    u16* p = qp + (((size_t)(b*HH + h)) * TT + t0) * DD + d;
                    #pragma unroll
                    for (int r = 0; r < 4; ++r) p[(size_t)r * DD] = bvv[r];
                } else {
                    const int ch = t0 >> 7, tc = t0 & (LCH-1);
                    u16* pt = (sel == 1 ? kt : vt)
                            + (((size_t)((b*HH + h)*NCH + ch)) * DD + d) * LCH + tc;
                    *(ushort4*)pt = make_ushort4(bvv[0], bvv[1], bvv[2], bvv[3]);
                    if (sel == 1) {
                        u16* p = kp + (((size_t)(b*HH + h)) * TT + t0) * DD + d;
                        #pragma unroll
                        for (int r = 0; r < 4; ++r) p[(size_t)r * DD] = bvv[r];
                    }
                }
            }
        }
    }
    #undef LDSA
    #undef LDSB
}

// Final GEMM: out[m,n] = sum_k y[m,k]*Wp[n,k] + bp[n]. BM=128, BN=64, dbuf LDS.
// R12: XCD-aware block swizzle (512 blocks, 512%8==0). XCD k owns by in [4k,4k+4)
// x all bx -> working set 4 ybf panels (1MB) + Wp (2MB) = 3MB < 4MB L2.
__global__ __launch_bounds__(256)
void lca_gemm_out(const u16* __restrict__ A, const u16* __restrict__ W,
                  const float* __restrict__ bias, float* __restrict__ out)
{
    __shared__ short As[2][4096];
    __shared__ short Bs2[2][2048];
    const int tid  = threadIdx.x;
    const int lane = tid & 63;
    const int wid  = tid >> 6;

    const int bid = blockIdx.y * gridDim.x + blockIdx.x;   // 0..511
    const int nb  = (bid & 7) * 64 + (bid >> 3);           // bijective (512%8==0)
    const int bm0 = (nb >> 4) * 128;                       // by' = nb/16 (0..31)
    const int bn0 = (nb & 15) * 64;                        // bx' = nb%16 (0..15)

    const int wm = wid >> 1, wn = wid & 1;

    const int rsA = wid*32 + (lane >> 2);
    const int rsB = wid*16 + (lane >> 2);
    const int kc  = (lane & 3) * 8;

    f32x4 acc[4][2];
    #pragma unroll
    for (int i = 0; i < 4; ++i)
        #pragma unroll
        for (int j = 0; j < 2; ++j)
            acc[i][j] = (f32x4){0.f, 0.f, 0.f, 0.f};

    const int rA = wm*64 + (lane & 15);
    const int rB = wn*32 + (lane & 15);
    const int kk = (lane >> 4) * 8;

    #pragma unroll
    for (int j = 0; j < 2; ++j)
        gload16(A + (size_t)(bm0 + rsA + j*16) * CC + kc, &As[0][wid*1024 + j*512]);
    gload16(W + (size_t)(bn0 + rsB) * CC + kc, &Bs2[0][wid*512]);
    __syncthreads();

    int cur = 0;
    for (int k0 = 0; k0 < CC; k0 += 32) {
        if (k0 + 32 < CC) {
            #pragma unroll
            for (int j = 0; j < 2; ++j)
                gload16(A + (size_t)(bm0 + rsA + j*16) * CC + k0 + 32 + kc, &As[cur^1][wid*1024 + j*512]);
            gload16(W + (size_t)(bn0 + rsB) * CC + k0 + 32 + kc, &Bs2[cur^1][wid*512]);
        }

        s16x8 af[4], bf[2];
        #pragma unroll
        for (int mi = 0; mi < 4; ++mi) af[mi] = *(const s16x8*)(&As[cur][(rA + mi*16)*32 + kk]);
        #pragma unroll
        for (int ni = 0; ni < 2; ++ni) bf[ni] = *(const s16x8*)(&Bs2[cur][(rB + ni*16)*32 + kk]);
        #pragma unroll
        for (int mi = 0; mi < 4; ++mi)
            #pragma unroll
            for (int ni = 0; ni < 2; ++ni)
                acc[mi][ni] = __builtin_amdgcn_mfma_f32_16x16x32_bf16(af[mi], bf[ni], acc[mi][ni], 0, 0, 0);

        __syncthreads();
        cur ^= 1;
    }

    #pragma unroll
    for (int mi = 0; mi < 4; ++mi) {
        #pragma unroll
        for (int ni = 0; ni < 2; ++ni) {
            const int col = bn0 + wn*32 + ni*16 + (lane & 15);
            const int rb  = bm0 + wm*64 + mi*16 + (lane >> 4)*4;
            const float bb = bias[col];
            #pragma unroll
            for (int r = 0; r < 4; ++r)
                out[(size_t)(rb + r) * CC + col] = acc[mi][ni][r] + bb;
        }
    }
}

// S for one chunk: acc[d-frag][e-frag] = sum_t kt[d][t]*vt[e][t]; ks = sum_t kt[lane][t]
__device__ __forceinline__ void chunk_S(const u16* __restrict__ kg, const u16* __restrict__ vg,
                                        int lr, int lk, int lane,
                                        f32x4 (&acc)[4][4], float& ks)
{
    #pragma unroll
    for (int mi = 0; mi < 4; ++mi)
        #pragma unroll
        for (int ni = 0; ni < 4; ++ni)
            acc[mi][ni] = (f32x4){0.f, 0.f, 0.f, 0.f};
    #pragma unroll
    for (int kss = 0; kss < 4; ++kss) {
        const int k = kss*32 + lk;
        s16x8 af[4], bf[4];
        #pragma unroll
        for (int mi = 0; mi < 4; ++mi) af[mi] = *(const s16x8*)(kg + (size_t)(mi*16 + lr)*LCH + k);
        #pragma unroll
        for (int ni = 0; ni < 4; ++ni) bf[ni] = *(const s16x8*)(vg + (size_t)(ni*16 + lr)*LCH + k);
        #pragma unroll
        for (int mi = 0; mi < 4; ++mi)
            #pragma unroll
            for (int ni = 0; ni < 4; ++ni)
                acc[mi][ni] = __builtin_amdgcn_mfma_f32_16x16x32_bf16(af[mi], bf[ni], acc[mi][ni], 0, 0, 0);
    }
    ks = 0.0f;
    #pragma unroll
    for (int i = 0; i < 16; ++i) {
        s16x8 dv = *(const s16x8*)(kg + (size_t)lane * LCH + i*8);
        #pragma unroll
        for (int j = 0; j < 8; ++j) ks += bf2f((u16)dv[j]);
    }
}

// Fused pass1+pass2: grid = 32 blocks (one per bh), 8 waves.
// Wave w computes S for chunks 2w, 2w+1 (MFMA, regs), totals to LDS,
// cross-wave exclusive scan, writes pst (bf16 transposed) + pksx + final states.
__global__ __launch_bounds__(512, 2)
void lca_pass12(const u16* __restrict__ kt, const u16* __restrict__ vt,
                u16* __restrict__ pst, float* __restrict__ pksx,
                float* __restrict__ out)
{
    extern __shared__ char P12[];          // 8*16384 (Tw f32) + 8*256 (ksw f32) = 133120 B
    float* Tw  = (float*)P12;              // [8][4096]
    float* ksw = (float*)(P12 + 131072);   // [8][64]

    const int bh  = blockIdx.x;
    const int tid = threadIdx.x;
    const int wid = tid >> 6, lane = tid & 63;
    const int lr = lane & 15, lg = lane >> 4;
    const int lk = lg * 8;
    const int c0 = wid * 2;

    const u16* kg0 = kt + ((size_t)bh * NCH + c0) * DD * LCH;
    const u16* vg0 = vt + ((size_t)bh * NCH + c0) * DD * LCH;

    f32x4 s0[4][4], s1[4][4];
    float ks0, ks1;
    chunk_S(kg0,              vg0,              lr, lk, lane, s0, ks0);
    chunk_S(kg0 + DD*LCH,     vg0 + DD*LCH,     lr, lk, lane, s1, ks1);

    // totals to LDS
    float* Tme = Tw + wid * 4096;
    #pragma unroll
    for (int mi = 0; mi < 4; ++mi)
        #pragma unroll
        for (int ni = 0; ni < 4; ++ni)
            #pragma unroll
            for (int r = 0; r < 4; ++r) {
                const int d = mi*16 + lg*4 + r;
                const int e = ni*16 + lr;
                Tme[d*64 + e] = s0[mi][ni][r] + s1[mi][ni][r];
            }
    ksw[wid*64 + lane] = ks0 + ks1;
    __syncthreads();

    // exclusive offsets over waves (chunk-pair order)
    f32x4 off[4][4];
    #pragma unroll
    for (int mi = 0; mi < 4; ++mi)
        #pragma unroll
        for (int ni = 0; ni < 4; ++ni)
            off[mi][ni] = (f32x4){0.f, 0.f, 0.f, 0.f};
    for (int w = 0; w < 8; ++w) {
        if (w >= wid) break;
        const float* Tp = Tw + w * 4096;
        #pragma unroll
        for (int mi = 0; mi < 4; ++mi)
            #pragma unroll
            for (int ni = 0; ni < 4; ++ni)
                #pragma unroll
                for (int r = 0; r < 4; ++r) {
                    const int d = mi*16 + lg*4 + r;
                    const int e = ni*16 + lr;
                    off[mi][ni][r] += Tp[d*64 + e];
                }
    }
    float koff = 0.0f;
    for (int w = 0; w < 8; ++w) {
        if (w >= wid) break;
        koff += ksw[w*64 + lane];
    }

    // pst (bf16, transposed [e][d]): chunk c0 = off; chunk c0+1 = off + s0
    u16* P0 = pst + ((size_t)bh * NCH + c0) * (DD*DD);
    u16* P1 = P0 + DD*DD;
    #pragma unroll
    for (int mi = 0; mi < 4; ++mi)
        #pragma unroll
        for (int ni = 0; ni < 4; ++ni)
            #pragma unroll
            for (int r = 0; r < 4; ++r) {
                const int d = mi*16 + lg*4 + r;
                const int e = ni*16 + lr;
                P0[(size_t)e * DD + d] = bf16r(off[mi][ni][r]);
                P1[(size_t)e * DD + d] = bf16r(off[mi][ni][r] + s0[mi][ni][r]);
            }
    pksx[((size_t)bh * NCH + c0) * DD + lane]     = koff;
    pksx[((size_t)bh * NCH + c0 + 1) * DD + lane] = koff + ks0;

    // final inclusive states from the last wave
    if (wid == 7) {
        float* nkv = out + OUT_OFF_KV + (size_t)bh * (DD*DD);
        #pragma unroll
        for (int mi = 0; mi < 4; ++mi)
            #pragma unroll
            for (int ni = 0; ni < 4; ++ni)
                #pragma unroll
                for (int r = 0; r < 4; ++r) {
                    const int d = mi*16 + lg*4 + r;
                    const int e = ni*16 + lr;
                    nkv[(size_t)d * DD + e] = off[mi][ni][r] + s0[mi][ni][r] + s1[mi][ni][r];
                }
        out[OUT_OFF_KSUM + (size_t)bh * DD + lane] = koff + ks0 + ks1;
    }
}

// Pass 3 (MFMA): scores = qp@kp^T (causal), den = rowsum + qp.pks + 1e-6,
// y = (qp@P^T + masked_scores@v) / den -> ybf (B,T,C) bf16
__global__ __launch_bounds__(256)
void lca_pass3(const u16* __restrict__ qp, const u16* __restrict__ kp,
               const u16* __restrict__ vt, const u16* __restrict__ pst,
               const float* __restrict__ pksx, u16* __restrict__ ybf)
{
    __shared__ short SA[16384];
    __shared__ short VS[8192];
    __shared__ short PS[4096];
    __shared__ float pks_s[DD];
    __shared__ float den_s[LCH];

    char* SAb = (char*)SA;
    char* VSb = (char*)VS;
    char* PSb = (char*)PS;

    const int c = blockIdx.x, bh = blockIdx.y;
    const int tid = threadIdx.x;
    const int lane = tid & 63, wid = tid >> 6;

    const u16* qg = qp + ((size_t)bh * TT + (size_t)c * LCH) * DD;
    const u16* kg = kp + ((size_t)bh * TT + (size_t)c * LCH) * DD;
    const u16* vg = vt + ((size_t)bh * NCH + c) * DD * LCH;
    const u16* pg = pst + ((size_t)bh * NCH + c) * (DD*DD);

    for (int i = tid; i < 1024; i += 256) {
        const int row = i >> 3, cc = i & 7;
        const s16x8 dv = *(const s16x8*)(qg + (size_t)row*DD + cc*8);
        *(s16x8*)(SAb + ((row*128 + cc*16) ^ ((row & 7) << 4))) = dv;
    }
    for (int i = tid; i < 1024; i += 256) {
        const int row = i >> 3, cc = i & 7;
        const s16x8 dv = *(const s16x8*)(kg + (size_t)row*DD + cc*8);
        *(s16x8*)(SAb + 16384 + ((row*128 + cc*16) ^ ((row & 7) << 4))) = dv;
    }
    for (int i = tid; i < 1024; i += 256) {
        const int row = i >> 4, cc = i & 15;
        const s16x8 dv = *(const s16x8*)(vg + (size_t)row*LCH + cc*8);
        *(s16x8*)(VSb + ((row*256 + cc*16) ^ ((row & 7) << 4))) = dv;
    }
    for (int i = tid; i < 512; i += 256) {
        const int row = i >> 3, cc = i & 7;
        const s16x8 dv = *(const s16x8*)(pg + (size_t)row*DD + cc*8);
        *(s16x8*)(PSb + ((row*128 + cc*16) ^ ((row & 7) << 4))) = dv;
    }
    if (tid < DD) pks_s[tid] = pksx[((size_t)bh * NCH + c) * DD + tid];
    __syncthreads();

    if (tid < LCH) {
        const int t = tid;
        float s = 1e-6f;
        #pragma unroll
        for (int cc = 0; cc < 8; ++cc) {
            const s16x8 dv = *(const s16x8*)(SAb + ((t*128 + cc*16) ^ ((t & 7) << 4)));
            #pragma unroll
            for (int j = 0; j < 8; ++j) s += bf2f((u16)dv[j]) * pks_s[cc*8 + j];
        }
        den_s[t] = s;
    }

    const int wrow0 = wid * 32;
    const int lr = lane & 15;
    const int lg = lane >> 4;
    const int lk = lg * 8;

    f32x4 sacc[2][8];
    #pragma unroll
    for (int mi = 0; mi < 2; ++mi)
        #pragma unroll
        for (int ni = 0; ni < 8; ++ni)
            sacc[mi][ni] = (f32x4){0.f, 0.f, 0.f, 0.f};

    #pragma unroll
    for (int ks = 0; ks < 2; ++ks) {
        const int k2 = (ks*32 + lk) * 2;
        s16x8 af[2];
        #pragma unroll
        for (int mi = 0; mi < 2; ++mi) {
            const int row = wrow0 + mi*16 + lr;
            af[mi] = *(const s16x8*)(SAb + ((row*128 + k2) ^ ((row & 7) << 4)));
        }
        #pragma unroll
        for (int ni = 0; ni < 8; ++ni) {
            const int rowb = ni*16 + lr;
            const s16x8 bf = *(const s16x8*)(SAb + 16384 + ((rowb*128 + k2) ^ ((rowb & 7) << 4)));
            sacc[0][ni] = __builtin_amdgcn_mfma_f32_16x16x32_bf16(af[0], bf, sacc[0][ni], 0, 0, 0);
            sacc[1][ni] = __builtin_amdgcn_mfma_f32_16x16x32_bf16(af[1], bf, sacc[1][ni], 0, 0, 0);
        }
    }

    f32x4 pv[2][4];
    #pragma unroll
    for (int mi = 0; mi < 2; ++mi)
        #pragma unroll
        for (int ni = 0; ni < 4; ++ni)
            pv[mi][ni] = (f32x4){0.f, 0.f, 0.f, 0.f};

    #pragma unroll
    for (int ks = 0; ks < 2; ++ks) {
        const int k2 = (ks*32 + lk) * 2;
        s16x8 af[2];
        #pragma unroll
        for (int mi = 0; mi < 2; ++mi) {
            const int row = wrow0 + mi*16 + lr;
            af[mi] = *(const s16x8*)(SAb + ((row*128 + k2) ^ ((row & 7) << 4)));
        }
        #pragma unroll
        for (int ni = 0; ni < 4; ++ni) {
            const int rowb = ni*16 + lr;
            const s16x8 bf = *(const s16x8*)(PSb + ((rowb*128 + k2) ^ ((rowb & 7) << 4)));
            pv[0][ni] = __builtin_amdgcn_mfma_f32_16x16x32_bf16(af[0], bf, pv[0][ni], 0, 0, 0);
            pv[1][ni] = __builtin_amdgcn_mfma_f32_16x16x32_bf16(af[1], bf, pv[1][ni], 0, 0, 0);
        }
    }
    __syncthreads();

    #pragma unroll
    for (int mi = 0; mi < 2; ++mi) {
        float dr[4] = {0.f, 0.f, 0.f, 0.f};
        #pragma unroll
        for (int ni = 0; ni < 8; ++ni) {
            const int tp = ni*16 + lr;
            #pragma unroll
            for (int r = 0; r < 4; ++r) {
                const int t = wrow0 + mi*16 + lg*4 + r;
                const float v = (tp <= t) ? sacc[mi][ni][r] : 0.f;
                dr[r] += v;
                *(u16*)(SAb + ((t*256 + tp*2) ^ ((t & 7) << 4))) = bf16r(v);
            }
        }
        #pragma unroll
        for (int r = 0; r < 4; ++r) {
            float s = dr[r];
            s += __shfl_xor(s, 1); s += __shfl_xor(s, 2);
            s += __shfl_xor(s, 4); s += __shfl_xor(s, 8);
            if (lr == 0) {
                const int t = wrow0 + mi*16 + lg*4 + r;
                den_s[t] += s;
            }
        }
    }
    __syncthreads();

    #pragma unroll
    for (int ks = 0; ks < 4; ++ks) {
        const int k2 = (ks*32 + lk) * 2;
        s16x8 af[2];
        #pragma unroll
        for (int mi = 0; mi < 2; ++mi) {
            const int row = wrow0 + mi*16 + lr;
            af[mi] = *(const s16x8*)(SAb + ((row*256 + k2) ^ ((row & 7) << 4)));
        }
        #pragma unroll
        for (int ni = 0; ni < 4; ++ni) {
            const int rowb = ni*16 + lr;
            const s16x8 bf = *(const s16x8*)(VSb + ((rowb*256 + k2) ^ ((rowb & 7) << 4)));
            pv[0][ni] = __builtin_amdgcn_mfma_f32_16x16x32_bf16(af[0], bf, pv[0][ni], 0, 0, 0);
            pv[1][ni] = __builtin_amdgcn_mfma_f32_16x16x32_bf16(af[1], bf, pv[1][ni], 0, 0, 0);
        }
    }

    const int b = bh >> 4, h = bh & (HH-1);
    #pragma unroll
    for (int mi = 0; mi < 2; ++mi)
        #pragma unroll
        for (int ni = 0; ni < 4; ++ni) {
            const int e = ni*16 + lr;
            #pragma unroll
            for (int r = 0; r < 4; ++r) {
                const int t = wrow0 + mi*16 + lg*4 + r;
                const float y = pv[mi][ni][r] / den_s[t];
                ybf[((size_t)(b*TT) + (size_t)c*LCH + t) * CC + h*DD + e] = bf16r(y);
            }
        }
}

extern "C" void kernel_launch(void* const* d_in, const int* in_sizes, int n_in,
                              void* d_out, int out_size, void* d_ws, size_t ws_size,
                              hipStream_t stream) {
    const float* x  = (const float*)d_in[0];
    const float* Wq = (const float*)d_in[1];
    const float* Wk = (const float*)d_in[2];
    const float* Wv = (const float*)d_in[3];
    const float* Wp = (const float*)d_in[4];
    const float* bp = (const float*)d_in[5];
    float* out = (float*)d_out;
    char* ws = (char*)d_ws;

    u16*   xbf  = (u16*)(ws + 0);
    u16*   Wbf  = (u16*)(ws + (size_t)8*MB);
    u16*   qp   = (u16*)(ws + (size_t)16*MB);
    u16*   kp   = (u16*)(ws + (size_t)24*MB);
    u16*   kt   = (u16*)(ws + (size_t)32*MB);
    u16*   vt   = (u16*)(ws + (size_t)40*MB);
    u16*   ybf  = (u16*)(ws + (size_t)48*MB);
    float* pksx = (float*)(ws + (size_t)64*MB + 131072);
    u16*   pst  = (u16*)(ws + (size_t)65*MB);

    (void)hipFuncSetAttribute((const void*)lca_gemm_qkv8,
                              hipFuncAttributeMaxDynamicSharedMemorySize, 131072);
    (void)hipFuncSetAttribute((const void*)lca_pass12,
                              hipFuncAttributeMaxDynamicSharedMemorySize, 133120);

    f2bf_all<<<4096, 256, 0, stream>>>(x, Wq, Wk, Wv, Wp, xbf, Wbf);

    lca_gemm_qkv8<<<dim3(3*CC/256, MM/256), 512, 131072, stream>>>(xbf, Wbf, qp, kp, kt, vt);

    lca_pass12<<<BHH, 512, 133120, stream>>>(kt, vt, pst, pksx, out);
    lca_pass3<<<dim3(NCH, BHH), 256, 0, stream>>>(qp, kp, vt, pst, pksx, ybf);

    lca_gemm_out<<<dim3(CC/64, MM/128), 256, 0, stream>>>(ybf, Wbf + ((size_t)3 << 20), bp, out);
}

// Round 13
// 124.749 us; speedup vs baseline: 1.4500x; 1.4500x over previous
//
#include <hip/hip_runtime.h>
#include <math.h>

#define BB 2
#define TT 2048
#define CC 1024
#define HH 16
#define DD 64
#define MM (BB*TT)
#define LCH 128
#define NCH (TT/LCH)
#define BHH (BB*HH)

#define OUT_OFF_KV   4194304
#define OUT_OFF_KSUM 4325376
#define MB 1048576

typedef unsigned int u32;
typedef unsigned short u16;
typedef __attribute__((ext_vector_type(8))) short s16x8;
typedef __attribute__((ext_vector_type(8))) unsigned short us8;
typedef __attribute__((ext_vector_type(4))) float f32x4;

__device__ __forceinline__ float fmap(float x) {
    return x > 0.0f ? x + 1.0f : expf(x);
}
__device__ __forceinline__ u16 bf16r(float f) {
    u32 u = __float_as_uint(f);
    u += 0x7fffu + ((u >> 16) & 1u);
    return (u16)(u >> 16);
}
__device__ __forceinline__ float bf2f(u16 u) {
    return __uint_as_float(((u32)u) << 16);
}
__device__ __forceinline__ void gload16(const void* g, void* l) {
    __builtin_amdgcn_global_load_lds(
        (const __attribute__((address_space(1))) u32*)g,
        (__attribute__((address_space(3))) u32*)l, 16, 0, 0);
}

// Fused fp32->bf16 cast: x then Wq,Wk,Wv,Wp into xbf and contiguous Wbf.
__global__ __launch_bounds__(256)
void f2bf_all(const float* __restrict__ x,
              const float* __restrict__ Wq, const float* __restrict__ Wk,
              const float* __restrict__ Wv, const float* __restrict__ Wp,
              u16* __restrict__ xbf, u16* __restrict__ wbf)
{
    const int i = blockIdx.x * 256 + threadIdx.x;   // 0 .. 1048575
    const float* src;
    u16* dst;
    int off;
    if (i < 524288) {
        src = x; dst = xbf; off = i;
    } else {
        const int j = i - 524288;
        const int sel = j >> 17;
        off = j & 131071;
        src = (sel == 0) ? Wq : (sel == 1) ? Wk : (sel == 2) ? Wv : Wp;
        dst = wbf + ((size_t)sel << 20);
    }
    const float4 a = ((const float4*)src)[off*2];
    const float4 b = ((const float4*)src)[off*2 + 1];
    us8 p;
    p[0]=bf16r(a.x); p[1]=bf16r(a.y); p[2]=bf16r(a.z); p[3]=bf16r(a.w);
    p[4]=bf16r(b.x); p[5]=bf16r(b.y); p[6]=bf16r(b.z); p[7]=bf16r(b.w);
    ((us8*)dst)[off] = p;
}

// ===== 8-phase helpers =====
__device__ __forceinline__ void read_a(const char* LB, int abase, int wm, int lr, int lg4,
                                       s16x8 (&af)[4][2])
{
    #pragma unroll
    for (int mi = 0; mi < 4; ++mi) {
        const int r = wm*64 + mi*16 + lr;
        #pragma unroll
        for (int ks = 0; ks < 2; ++ks) {
            const int gg = (ks*4 + lg4) ^ (r & 7);
            af[mi][ks] = *(const s16x8*)(LB + abase + r*128 + gg*16);
        }
    }
}
__device__ __forceinline__ void read_b(const char* LB, int bbase, int wn, int lr, int lg4,
                                       s16x8 (&bv)[2][2])
{
    #pragma unroll
    for (int ni = 0; ni < 2; ++ni) {
        const int r = wn*32 + ni*16 + lr;
        #pragma unroll
        for (int ks = 0; ks < 2; ++ks) {
            const int gg = (ks*4 + lg4) ^ (r & 7);
            bv[ni][ks] = *(const s16x8*)(LB + bbase + r*128 + gg*16);
        }
    }
}
__device__ __forceinline__ void phase_mfma(const s16x8 (&af)[4][2], const s16x8 (&bv)[2][2],
                                           f32x4 (&acc)[4][2])
{
    #pragma unroll
    for (int mi = 0; mi < 4; ++mi)
        #pragma unroll
        for (int ni = 0; ni < 2; ++ni)
            #pragma unroll
            for (int ks = 0; ks < 2; ++ks)
                acc[mi][ni] = __builtin_amdgcn_mfma_f32_16x16x32_bf16(
                    af[mi][ks], bv[ni][ks], acc[mi][ni], 0, 0, 0);
}

// ==================== 8-phase 256x256 QKV GEMM (read-ahead pipeline, R11) ====================
__global__ __launch_bounds__(512, 2)
void lca_gemm_qkv8(const u16* __restrict__ A, const u16* __restrict__ Wall,
                   u16* __restrict__ qp, u16* __restrict__ kp,
                   u16* __restrict__ kt, u16* __restrict__ vt)
{
    extern __shared__ char LB[];    // 131072 bytes
    const int tid  = threadIdx.x;
    const int lane = tid & 63;
    const int wid  = tid >> 6;      // 0..7
    const int wm   = wid >> 2;      // 0..1
    const int wn   = wid & 3;       // 0..3
    const int bm0  = blockIdx.y * 256;
    const int bn0g = blockIdx.x * 256;
    const int sel  = bn0g >> 10;    // 0,1,2
    const int nn0  = bn0g & (CC-1);
    const u16* W = Wall + ((size_t)sel << 20);
    const int NT = CC / 64;         // 16 K-tiles

    const int srow = (wid << 3) + (lane >> 3);   // 0..63 within sweep
    const int sg   = lane & 7;
    auto STAGE = [&](const u16* G, int ldsbase) {
        #pragma unroll
        for (int j = 0; j < 2; ++j) {
            const int r  = j*64 + srow;
            const int gs = sg ^ (r & 7);
            gload16(G + (size_t)r * CC + gs*8,
                    LB + ldsbase + (size_t)(j*64 + (wid<<3))*128);
        }
    };
    #define LDSA(slot,h) (((slot)*2 + (h))*16384)
    #define LDSB(slot,h) (65536 + ((slot)*2 + (h))*16384)

    f32x4 acc[4][4][2];
    #pragma unroll
    for (int q = 0; q < 4; ++q)
        #pragma unroll
        for (int mi = 0; mi < 4; ++mi)
            #pragma unroll
            for (int ni = 0; ni < 2; ++ni)
                acc[q][mi][ni] = (f32x4){0.f, 0.f, 0.f, 0.f};

    STAGE(A + (size_t)(bm0      ) * CC + 0,  LDSA(0,0));
    STAGE(A + (size_t)(bm0 + 128) * CC + 0,  LDSA(0,1));
    STAGE(W + (size_t)(nn0      ) * CC + 0,  LDSB(0,0));
    STAGE(W + (size_t)(nn0 + 128) * CC + 0,  LDSB(0,1));
    STAGE(A + (size_t)(bm0      ) * CC + 64, LDSA(1,0));
    STAGE(W + (size_t)(nn0      ) * CC + 64, LDSB(1,0));
    asm volatile("s_waitcnt vmcnt(4)" ::: "memory");
    __builtin_amdgcn_s_barrier();

    const int lr  = lane & 15;
    const int lg4 = lane >> 4;      // 0..3

    s16x8 afr0[4][2], afr1[4][2], b0r[2][2], b1r[2][2];
    read_a(LB, LDSA(0,0), wm, lr, lg4, afr0);
    read_b(LB, LDSB(0,0), wn, lr, lg4, b0r);

    for (int t = 0; t < NT; ++t) {
        const int slot  = t & 1;
        const int nslot = slot ^ 1;

        // q0: stage A1(t+1); read b1=B1(t); MFMA(afr0,b0r)
        if (t+1 < NT) STAGE(A + (size_t)(bm0 + 128)*CC + (t+1)*64, LDSA(nslot,1));
        read_b(LB, LDSB(slot,1), wn, lr, lg4, b1r);
        __builtin_amdgcn_sched_barrier(0);
        if (t < NT-1) asm volatile("s_waitcnt vmcnt(6)" ::: "memory");
        asm volatile("s_waitcnt lgkmcnt(4)" ::: "memory");
        __builtin_amdgcn_sched_barrier(0);
        __builtin_amdgcn_s_setprio(1);
        phase_mfma(afr0, b0r, acc[0]);
        __builtin_amdgcn_s_setprio(0);
        __builtin_amdgcn_sched_barrier(0);
        __builtin_amdgcn_s_barrier();

        // q1: stage B1(t+1); read afr1=A1(t); MFMA(afr0,b1r)
        if (t+1 < NT) STAGE(W + (size_t)(nn0 + 128)*CC + (t+1)*64, LDSB(nslot,1));
        read_a(LB, LDSA(slot,1), wm, lr, lg4, afr1);
        __builtin_amdgcn_sched_barrier(0);
        if (t < NT-1) asm volatile("s_waitcnt vmcnt(6)" ::: "memory");
        asm volatile("s_waitcnt lgkmcnt(8)" ::: "memory");
        __builtin_amdgcn_sched_barrier(0);
        __builtin_amdgcn_s_setprio(1);
        phase_mfma(afr0, b1r, acc[1]);
        __builtin_amdgcn_s_setprio(0);
        __builtin_amdgcn_sched_barrier(0);
        __builtin_amdgcn_s_barrier();

        // q2: stage A0(t+2); no reads; MFMA(afr1,b0r)
        if (t+2 < NT) STAGE(A + (size_t)(bm0)*CC + (t+2)*64, LDSA(slot,0));
        __builtin_amdgcn_sched_barrier(0);
        if (t < NT-1) asm volatile("s_waitcnt vmcnt(4)" ::: "memory");
        asm volatile("s_waitcnt lgkmcnt(0)" ::: "memory");
        __builtin_amdgcn_sched_barrier(0);
        __builtin_amdgcn_s_setprio(1);
        phase_mfma(afr1, b0r, acc[2]);
        __builtin_amdgcn_s_setprio(0);
        __builtin_amdgcn_sched_barrier(0);
        __builtin_amdgcn_s_barrier();

        // q3: stage B0(t+2); read afr0=A0(t+1), b0r=B0(t+1); MFMA(afr1,b1r)
        if (t+2 < NT) STAGE(W + (size_t)(nn0)*CC + (t+2)*64, LDSB(slot,0));
        if (t+1 < NT) {
            read_a(LB, LDSA(nslot,0), wm, lr, lg4, afr0);
            read_b(LB, LDSB(nslot,0), wn, lr, lg4, b0r);
        }
        __builtin_amdgcn_sched_barrier(0);
        if (t < NT-2)       asm volatile("s_waitcnt vmcnt(4)" ::: "memory");
        else if (t == NT-2) asm volatile("s_waitcnt vmcnt(0)" ::: "memory");
        __builtin_amdgcn_sched_barrier(0);
        __builtin_amdgcn_s_setprio(1);
        phase_mfma(afr1, b1r, acc[3]);
        __builtin_amdgcn_s_setprio(0);
        __builtin_amdgcn_sched_barrier(0);
        __builtin_amdgcn_s_barrier();
    }

    // epilogue: scalar stores (proven, incl. nn0 fix)
    #pragma unroll
    for (int q = 0; q < 4; ++q) {
        const int mh = q >> 1, nh = q & 1;
        #pragma unroll
        for (int mi = 0; mi < 4; ++mi) {
            #pragma unroll
            for (int ni = 0; ni < 2; ++ni) {
                const int coln = nn0 + nh*128 + wn*32 + ni*16 + lr;
                const int rb   = bm0 + mh*128 + wm*64 + mi*16 + lg4*4;
                const int h = coln >> 6, d = coln & (DD-1);
                const int b = rb >> 11, t0 = rb & (TT-1);
                u16 bvv[4];
                #pragma unroll
                for (int r = 0; r < 4; ++r) {
                    float val = acc[q][mi][ni][r];
                    if (sel != 2) val = fmap(val);
                    bvv[r] = bf16r(val);
                }
                if (sel == 0) {
                    u16* p = qp + (((size_t)(b*HH + h)) * TT + t0) * DD + d;
                    #pragma unroll
                    for (int r = 0; r < 4; ++r) p[(size_t)r * DD] = bvv[r];
                } else {
                    const int ch = t0 >> 7, tc = t0 & (LCH-1);
                    u16* pt = (sel == 1 ? kt : vt)
                            + (((size_t)((b*HH + h)*NCH + ch)) * DD + d) * LCH + tc;
                    *(ushort4*)pt = make_ushort4(bvv[0], bvv[1], bvv[2], bvv[3]);
                    if (sel == 1) {
                        u16* p = kp + (((size_t)(b*HH + h)) * TT + t0) * DD + d;
                        #pragma unroll
                        for (int r = 0; r < 4; ++r) p[(size_t)r * DD] = bvv[r];
                    }
                }
            }
        }
    }
    #undef LDSA
    #undef LDSB
}

// Final GEMM: out[m,n] = sum_k y[m,k]*Wp[n,k] + bp[n]. BM=128, BN=64, dbuf LDS.
// XCD-aware block swizzle (512 blocks, 512%8==0): XCD k owns by in [4k,4k+4).
__global__ __launch_bounds__(256)
void lca_gemm_out(const u16* __restrict__ A, const u16* __restrict__ W,
                  const float* __restrict__ bias, float* __restrict__ out)
{
    __shared__ short As[2][4096];
    __shared__ short Bs2[2][2048];
    const int tid  = threadIdx.x;
    const int lane = tid & 63;
    const int wid  = tid >> 6;

    const int bid = blockIdx.y * gridDim.x + blockIdx.x;   // 0..511
    const int nb  = (bid & 7) * 64 + (bid >> 3);           // bijective (512%8==0)
    const int bm0 = (nb >> 4) * 128;
    const int bn0 = (nb & 15) * 64;

    const int wm = wid >> 1, wn = wid & 1;

    const int rsA = wid*32 + (lane >> 2);
    const int rsB = wid*16 + (lane >> 2);
    const int kc  = (lane & 3) * 8;

    f32x4 acc[4][2];
    #pragma unroll
    for (int i = 0; i < 4; ++i)
        #pragma unroll
        for (int j = 0; j < 2; ++j)
            acc[i][j] = (f32x4){0.f, 0.f, 0.f, 0.f};

    const int rA = wm*64 + (lane & 15);
    const int rB = wn*32 + (lane & 15);
    const int kk = (lane >> 4) * 8;

    #pragma unroll
    for (int j = 0; j < 2; ++j)
        gload16(A + (size_t)(bm0 + rsA + j*16) * CC + kc, &As[0][wid*1024 + j*512]);
    gload16(W + (size_t)(bn0 + rsB) * CC + kc, &Bs2[0][wid*512]);
    __syncthreads();

    int cur = 0;
    for (int k0 = 0; k0 < CC; k0 += 32) {
        if (k0 + 32 < CC) {
            #pragma unroll
            for (int j = 0; j < 2; ++j)
                gload16(A + (size_t)(bm0 + rsA + j*16) * CC + k0 + 32 + kc, &As[cur^1][wid*1024 + j*512]);
            gload16(W + (size_t)(bn0 + rsB) * CC + k0 + 32 + kc, &Bs2[cur^1][wid*512]);
        }

        s16x8 af[4], bf[2];
        #pragma unroll
        for (int mi = 0; mi < 4; ++mi) af[mi] = *(const s16x8*)(&As[cur][(rA + mi*16)*32 + kk]);
        #pragma unroll
        for (int ni = 0; ni < 2; ++ni) bf[ni] = *(const s16x8*)(&Bs2[cur][(rB + ni*16)*32 + kk]);
        #pragma unroll
        for (int mi = 0; mi < 4; ++mi)
            #pragma unroll
            for (int ni = 0; ni < 2; ++ni)
                acc[mi][ni] = __builtin_amdgcn_mfma_f32_16x16x32_bf16(af[mi], bf[ni], acc[mi][ni], 0, 0, 0);

        __syncthreads();
        cur ^= 1;
    }

    #pragma unroll
    for (int mi = 0; mi < 4; ++mi) {
        #pragma unroll
        for (int ni = 0; ni < 2; ++ni) {
            const int col = bn0 + wn*32 + ni*16 + (lane & 15);
            const int rb  = bm0 + wm*64 + mi*16 + (lane >> 4)*4;
            const float bb = bias[col];
            #pragma unroll
            for (int r = 0; r < 4; ++r)
                out[(size_t)(rb + r) * CC + col] = acc[mi][ni][r] + bb;
        }
    }
}

// Pass 1 (MFMA): per (b,h,chunk): S[d][e] = sum_t kt[d][t]*vt[e][t]; ksum[d]
__global__ __launch_bounds__(256)
void lca_pass1(const u16* __restrict__ kt, const u16* __restrict__ vt,
               float* __restrict__ Sloc, float* __restrict__ ksloc)
{
    const int wid = threadIdx.x >> 6, lane = threadIdx.x & 63;
    const int c = blockIdx.x * 4 + wid, bh = blockIdx.y;
    const u16* kg = kt + ((size_t)bh * NCH + c) * DD * LCH;
    const u16* vg = vt + ((size_t)bh * NCH + c) * DD * LCH;
    const int lr = lane & 15;
    const int lk = (lane >> 4) * 8;

    f32x4 acc[4][4];
    #pragma unroll
    for (int i = 0; i < 4; ++i)
        #pragma unroll
        for (int j = 0; j < 4; ++j)
            acc[i][j] = (f32x4){0.f, 0.f, 0.f, 0.f};

    #pragma unroll
    for (int ks = 0; ks < 4; ++ks) {
        const int k = ks*32 + lk;
        s16x8 af[4], bf[4];
        #pragma unroll
        for (int mi = 0; mi < 4; ++mi) af[mi] = *(const s16x8*)(kg + (size_t)(mi*16 + lr)*LCH + k);
        #pragma unroll
        for (int ni = 0; ni < 4; ++ni) bf[ni] = *(const s16x8*)(vg + (size_t)(ni*16 + lr)*LCH + k);
        #pragma unroll
        for (int mi = 0; mi < 4; ++mi)
            #pragma unroll
            for (int ni = 0; ni < 4; ++ni)
                acc[mi][ni] = __builtin_amdgcn_mfma_f32_16x16x32_bf16(af[mi], bf[ni], acc[mi][ni], 0, 0, 0);
    }

    float* So = Sloc + ((size_t)bh * NCH + c) * (DD*DD);
    #pragma unroll
    for (int mi = 0; mi < 4; ++mi)
        #pragma unroll
        for (int ni = 0; ni < 4; ++ni) {
            const int e = ni*16 + lr;
            #pragma unroll
            for (int r = 0; r < 4; ++r) {
                const int d = mi*16 + (lane >> 4)*4 + r;
                So[(size_t)d * DD + e] = acc[mi][ni][r];
            }
        }

    float s = 0.0f;
    #pragma unroll
    for (int i = 0; i < 16; ++i) {
        s16x8 dv = *(const s16x8*)(kg + (size_t)lane * LCH + i*8);
        #pragma unroll
        for (int j = 0; j < 8; ++j) s += bf2f((u16)dv[j]);
    }
    ksloc[((size_t)bh * NCH + c) * DD + lane] = s;
}

// Pass 2: per (b,h): exclusive scan -> pst (bf16 transposed), pksx, states.
__global__ __launch_bounds__(256)
void lca_pass2(const float* __restrict__ Sloc, const float* __restrict__ ksloc,
               u16* __restrict__ pst, float* __restrict__ pksx,
               float* __restrict__ out)
{
    const int bh = blockIdx.x;
    const int tid = threadIdx.x;
    const int d0 = (tid >> 4) * 4;
    const int e0 = (tid & 15) * 4;

    float run[4][4] = {};
    for (int c = 0; c < NCH; ++c) {
        u16* P = pst + ((size_t)bh * NCH + c) * (DD*DD);
        #pragma unroll
        for (int i = 0; i < 4; ++i)
            #pragma unroll
            for (int j = 0; j < 4; ++j)
                P[(size_t)(e0 + j) * DD + (d0 + i)] = bf16r(run[i][j]);
        const float* S = Sloc + ((size_t)bh * NCH + c) * (DD*DD);
        #pragma unroll
        for (int i = 0; i < 4; ++i) {
            const float4 t4 = *(const float4*)(S + (size_t)(d0 + i) * DD + e0);
            run[i][0] += t4.x; run[i][1] += t4.y; run[i][2] += t4.z; run[i][3] += t4.w;
        }
    }
    float* nkv = out + OUT_OFF_KV + (size_t)bh * (DD*DD);
    #pragma unroll
    for (int i = 0; i < 4; ++i)
        *(float4*)(nkv + (size_t)(d0 + i) * DD + e0) =
            make_float4(run[i][0], run[i][1], run[i][2], run[i][3]);

    if (tid < DD) {
        float r = 0.0f;
        for (int c = 0; c < NCH; ++c) {
            pksx[((size_t)bh * NCH + c) * DD + tid] = r;
            r += ksloc[((size_t)bh * NCH + c) * DD + tid];
        }
        out[OUT_OFF_KSUM + (size_t)bh * DD + tid] = r;
    }
}

// Pass 3 (MFMA): scores = qp@kp^T (causal), den = rowsum + qp.pks + 1e-6,
// y = (qp@P^T + masked_scores@v) / den -> ybf (B,T,C) bf16
__global__ __launch_bounds__(256)
void lca_pass3(const u16* __restrict__ qp, const u16* __restrict__ kp,
               const u16* __restrict__ vt, const u16* __restrict__ pst,
               const float* __restrict__ pksx, u16* __restrict__ ybf)
{
    __shared__ short SA[16384];
    __shared__ short VS[8192];
    __shared__ short PS[4096];
    __shared__ float pks_s[DD];
    __shared__ float den_s[LCH];

    char* SAb = (char*)SA;
    char* VSb = (char*)VS;
    char* PSb = (char*)PS;

    const int c = blockIdx.x, bh = blockIdx.y;
    const int tid = threadIdx.x;
    const int lane = tid & 63, wid = tid >> 6;

    const u16* qg = qp + ((size_t)bh * TT + (size_t)c * LCH) * DD;
    const u16* kg = kp + ((size_t)bh * TT + (size_t)c * LCH) * DD;
    const u16* vg = vt + ((size_t)bh * NCH + c) * DD * LCH;
    const u16* pg = pst + ((size_t)bh * NCH + c) * (DD*DD);

    for (int i = tid; i < 1024; i += 256) {
        const int row = i >> 3, cc = i & 7;
        const s16x8 dv = *(const s16x8*)(qg + (size_t)row*DD + cc*8);
        *(s16x8*)(SAb + ((row*128 + cc*16) ^ ((row & 7) << 4))) = dv;
    }
    for (int i = tid; i < 1024; i += 256) {
        const int row = i >> 3, cc = i & 7;
        const s16x8 dv = *(const s16x8*)(kg + (size_t)row*DD + cc*8);
        *(s16x8*)(SAb + 16384 + ((row*128 + cc*16) ^ ((row & 7) << 4))) = dv;
    }
    for (int i = tid; i < 1024; i += 256) {
        const int row = i >> 4, cc = i & 15;
        const s16x8 dv = *(const s16x8*)(vg + (size_t)row*LCH + cc*8);
        *(s16x8*)(VSb + ((row*256 + cc*16) ^ ((row & 7) << 4))) = dv;
    }
    for (int i = tid; i < 512; i += 256) {
        const int row = i >> 3, cc = i & 7;
        const s16x8 dv = *(const s16x8*)(pg + (size_t)row*DD + cc*8);
        *(s16x8*)(PSb + ((row*128 + cc*16) ^ ((row & 7) << 4))) = dv;
    }
    if (tid < DD) pks_s[tid] = pksx[((size_t)bh * NCH + c) * DD + tid];
    __syncthreads();

    if (tid < LCH) {
        const int t = tid;
        float s = 1e-6f;
        #pragma unroll
        for (int cc = 0; cc < 8; ++cc) {
            const s16x8 dv = *(const s16x8*)(SAb + ((t*128 + cc*16) ^ ((t & 7) << 4)));
            #pragma unroll
            for (int j = 0; j < 8; ++j) s += bf2f((u16)dv[j]) * pks_s[cc*8 + j];
        }
        den_s[t] = s;
    }

    const int wrow0 = wid * 32;
    const int lr = lane & 15;
    const int lg = lane >> 4;
    const int lk = lg * 8;

    f32x4 sacc[2][8];
    #pragma unroll
    for (int mi = 0; mi < 2; ++mi)
        #pragma unroll
        for (int ni = 0; ni < 8; ++ni)
            sacc[mi][ni] = (f32x4){0.f, 0.f, 0.f, 0.f};

    #pragma unroll
    for (int ks = 0; ks < 2; ++ks) {
        const int k2 = (ks*32 + lk) * 2;
        s16x8 af[2];
        #pragma unroll
        for (int mi = 0; mi < 2; ++mi) {
            const int row = wrow0 + mi*16 + lr;
            af[mi] = *(const s16x8*)(SAb + ((row*128 + k2) ^ ((row & 7) << 4)));
        }
        #pragma unroll
        for (int ni = 0; ni < 8; ++ni) {
            const int rowb = ni*16 + lr;
            const s16x8 bf = *(const s16x8*)(SAb + 16384 + ((rowb*128 + k2) ^ ((rowb & 7) << 4)));
            sacc[0][ni] = __builtin_amdgcn_mfma_f32_16x16x32_bf16(af[0], bf, sacc[0][ni], 0, 0, 0);
            sacc[1][ni] = __builtin_amdgcn_mfma_f32_16x16x32_bf16(af[1], bf, sacc[1][ni], 0, 0, 0);
        }
    }

    f32x4 pv[2][4];
    #pragma unroll
    for (int mi = 0; mi < 2; ++mi)
        #pragma unroll
        for (int ni = 0; ni < 4; ++ni)
            pv[mi][ni] = (f32x4){0.f, 0.f, 0.f, 0.f};

    #pragma unroll
    for (int ks = 0; ks < 2; ++ks) {
        const int k2 = (ks*32 + lk) * 2;
        s16x8 af[2];
        #pragma unroll
        for (int mi = 0; mi < 2; ++mi) {
            const int row = wrow0 + mi*16 + lr;
            af[mi] = *(const s16x8*)(SAb + ((row*128 + k2) ^ ((row & 7) << 4)));
        }
        #pragma unroll
        for (int ni = 0; ni < 4; ++ni) {
            const int rowb = ni*16 + lr;
            const s16x8 bf = *(const s16x8*)(PSb + ((rowb*128 + k2) ^ ((rowb & 7) << 4)));
            pv[0][ni] = __builtin_amdgcn_mfma_f32_16x16x32_bf16(af[0], bf, pv[0][ni], 0, 0, 0);
            pv[1][ni] = __builtin_amdgcn_mfma_f32_16x16x32_bf16(af[1], bf, pv[1][ni], 0, 0, 0);
        }
    }
    __syncthreads();

    #pragma unroll
    for (int mi = 0; mi < 2; ++mi) {
        float dr[4] = {0.f, 0.f, 0.f, 0.f};
        #pragma unroll
        for (int ni = 0; ni < 8; ++ni) {
            const int tp = ni*16 + lr;
            #pragma unroll
            for (int r = 0; r < 4; ++r) {
                const int t = wrow0 + mi*16 + lg*4 + r;
                const float v = (tp <= t) ? sacc[mi][ni][r] : 0.f;
                dr[r] += v;
                *(u16*)(SAb + ((t*256 + tp*2) ^ ((t & 7) << 4))) = bf16r(v);
            }
        }
        #pragma unroll
        for (int r = 0; r < 4; ++r) {
            float s = dr[r];
            s += __shfl_xor(s, 1); s += __shfl_xor(s, 2);
            s += __shfl_xor(s, 4); s += __shfl_xor(s, 8);
            if (lr == 0) {
                const int t = wrow0 + mi*16 + lg*4 + r;
                den_s[t] += s;
            }
        }
    }
    __syncthreads();

    #pragma unroll
    for (int ks = 0; ks < 4; ++ks) {
        const int k2 = (ks*32 + lk) * 2;
        s16x8 af[2];
        #pragma unroll
        for (int mi = 0; mi < 2; ++mi) {
            const int row = wrow0 + mi*16 + lr;
            af[mi] = *(const s16x8*)(SAb + ((row*256 + k2) ^ ((row & 7) << 4)));
        }
        #pragma unroll
        for (int ni = 0; ni < 4; ++ni) {
            const int rowb = ni*16 + lr;
            const s16x8 bf = *(const s16x8*)(VSb + ((rowb*256 + k2) ^ ((rowb & 7) << 4)));
            pv[0][ni] = __builtin_amdgcn_mfma_f32_16x16x32_bf16(af[0], bf, pv[0][ni], 0, 0, 0);
            pv[1][ni] = __builtin_amdgcn_mfma_f32_16x16x32_bf16(af[1], bf, pv[1][ni], 0, 0, 0);
        }
    }

    const int b = bh >> 4, h = bh & (HH-1);
    #pragma unroll
    for (int mi = 0; mi < 2; ++mi)
        #pragma unroll
        for (int ni = 0; ni < 4; ++ni) {
            const int e = ni*16 + lr;
            #pragma unroll
            for (int r = 0; r < 4; ++r) {
                const int t = wrow0 + mi*16 + lg*4 + r;
                const float y = pv[mi][ni][r] / den_s[t];
                ybf[((size_t)(b*TT) + (size_t)c*LCH + t) * CC + h*DD + e] = bf16r(y);
            }
        }
}

extern "C" void kernel_launch(void* const* d_in, const int* in_sizes, int n_in,
                              void* d_out, int out_size, void* d_ws, size_t ws_size,
                              hipStream_t stream) {
    const float* x  = (const float*)d_in[0];
    const float* Wq = (const float*)d_in[1];
    const float* Wk = (const float*)d_in[2];
    const float* Wv = (const float*)d_in[3];
    const float* Wp = (const float*)d_in[4];
    const float* bp = (const float*)d_in[5];
    float* out = (float*)d_out;
    char* ws = (char*)d_ws;

    u16*   xbf  = (u16*)(ws + 0);
    u16*   Wbf  = (u16*)(ws + (size_t)8*MB);
    u16*   qp   = (u16*)(ws + (size_t)16*MB);
    u16*   kp   = (u16*)(ws + (size_t)24*MB);
    u16*   kt   = (u16*)(ws + (size_t)32*MB);
    u16*   vt   = (u16*)(ws + (size_t)40*MB);
    u16*   ybf  = (u16*)(ws + (size_t)48*MB);
    float* Sl   = (float*)(ws + (size_t)56*MB);
    float* ksl  = (float*)(ws + (size_t)64*MB);
    float* pksx = (float*)(ws + (size_t)64*MB + 131072);
    u16*   pst  = (u16*)(ws + (size_t)65*MB);

    (void)hipFuncSetAttribute((const void*)lca_gemm_qkv8,
                              hipFuncAttributeMaxDynamicSharedMemorySize, 131072);

    f2bf_all<<<4096, 256, 0, stream>>>(x, Wq, Wk, Wv, Wp, xbf, Wbf);

    lca_gemm_qkv8<<<dim3(3*CC/256, MM/256), 512, 131072, stream>>>(xbf, Wbf, qp, kp, kt, vt);

    lca_pass1<<<dim3(NCH/4, BHH), 256, 0, stream>>>(kt, vt, Sl, ksl);
    lca_pass2<<<BHH, 256, 0, stream>>>(Sl, ksl, pst, pksx, out);
    lca_pass3<<<dim3(NCH, BHH), 256, 0, stream>>>(qp, kp, vt, pst, pksx, ybf);

    lca_gemm_out<<<dim3(CC/64, MM/128), 256, 0, stream>>>(ybf, Wbf + ((size_t)3 << 20), bp, out);
}

// Round 14
// 116.906 us; speedup vs baseline: 1.5473x; 1.0671x over previous
//
#include <hip/hip_runtime.h>
#include <math.h>

#define BB 2
#define TT 2048
#define CC 1024
#define HH 16
#define DD 64
#define MM (BB*TT)
#define LCH 128
#define NCH (TT/LCH)
#define BHH (BB*HH)

#define OUT_OFF_KV   4194304
#define OUT_OFF_KSUM 4325376
#define MB 1048576

typedef unsigned int u32;
typedef unsigned short u16;
typedef __attribute__((ext_vector_type(8))) short s16x8;
typedef __attribute__((ext_vector_type(8))) unsigned short us8;
typedef __attribute__((ext_vector_type(4))) float f32x4;

__device__ __forceinline__ float fmap(float x) {
    return x > 0.0f ? x + 1.0f : expf(x);
}
__device__ __forceinline__ u16 bf16r(float f) {
    u32 u = __float_as_uint(f);
    u += 0x7fffu + ((u >> 16) & 1u);
    return (u16)(u >> 16);
}
__device__ __forceinline__ float bf2f(u16 u) {
    return __uint_as_float(((u32)u) << 16);
}
__device__ __forceinline__ void gload16(const void* g, void* l) {
    __builtin_amdgcn_global_load_lds(
        (const __attribute__((address_space(1))) u32*)g,
        (__attribute__((address_space(3))) u32*)l, 16, 0, 0);
}

// Fused fp32->bf16 cast: x then Wq,Wk,Wv,Wp into xbf and contiguous Wbf.
__global__ __launch_bounds__(256)
void f2bf_all(const float* __restrict__ x,
              const float* __restrict__ Wq, const float* __restrict__ Wk,
              const float* __restrict__ Wv, const float* __restrict__ Wp,
              u16* __restrict__ xbf, u16* __restrict__ wbf)
{
    const int i = blockIdx.x * 256 + threadIdx.x;   // 0 .. 1048575
    const float* src;
    u16* dst;
    int off;
    if (i < 524288) {
        src = x; dst = xbf; off = i;
    } else {
        const int j = i - 524288;
        const int sel = j >> 17;
        off = j & 131071;
        src = (sel == 0) ? Wq : (sel == 1) ? Wk : (sel == 2) ? Wv : Wp;
        dst = wbf + ((size_t)sel << 20);
    }
    const float4 a = ((const float4*)src)[off*2];
    const float4 b = ((const float4*)src)[off*2 + 1];
    us8 p;
    p[0]=bf16r(a.x); p[1]=bf16r(a.y); p[2]=bf16r(a.z); p[3]=bf16r(a.w);
    p[4]=bf16r(b.x); p[5]=bf16r(b.y); p[6]=bf16r(b.z); p[7]=bf16r(b.w);
    ((us8*)dst)[off] = p;
}

// ==================== 128x128 BK=64 QKV GEMM, 8 waves, 2 blocks/CU ====================
// C[m,n] = sum_k x[m,k]*W[n,k], N=3072 (Wq|Wk|Wv), K=1024.
// 8 waves (2M x 4N), wave tile 64x32. LDS 64KB: A[2][128x64], B[2][128x64] (swizzled).
// Iter t: {issue stage(t+1) -> slot (t+1)&1; vmcnt(keep 4); barrier;
//          12 ds_read_b128; MFMA x16; barrier}.
// Race check: stage(t+1) overwrites slot (t-1)&1 whose reads finished before the
// previous iter's 2nd barrier. Tail: vmcnt(0) at t=NT-1.
__global__ __launch_bounds__(512, 4)
void lca_gemm_qkv128(const u16* __restrict__ A, const u16* __restrict__ Wall,
                     u16* __restrict__ qp, u16* __restrict__ kp,
                     u16* __restrict__ kt, u16* __restrict__ vt)
{
    extern __shared__ char LB[];    // 65536 bytes: A slots @0,16K; B slots @32K,48K
    const int tid  = threadIdx.x;
    const int lane = tid & 63;
    const int wid  = tid >> 6;      // 0..7
    const int wm   = wid >> 2;      // 0..1
    const int wn   = wid & 3;       // 0..3
    const int bm0  = blockIdx.y * 128;
    const int bn0g = blockIdx.x * 128;
    const int sel  = bn0g >> 10;    // 0,1,2
    const int nn0  = bn0g & (CC-1);
    const u16* W = Wall + ((size_t)sel << 20);
    const int NT = CC / 64;         // 16 K-tiles

    // stage one 128x64 tile: 2 sweeps x 1 gload16/thread (8KB per sweep)
    const int srow = (wid << 3) + (lane >> 3);   // 0..63 within sweep
    const int sg   = lane & 7;
    auto STAGE = [&](const u16* G, int ldsbase) {
        #pragma unroll
        for (int j = 0; j < 2; ++j) {
            const int r  = j*64 + srow;
            const int gs = sg ^ (r & 7);
            gload16(G + (size_t)r * CC + gs*8,
                    LB + ldsbase + (size_t)(j*64 + (wid<<3))*128);
        }
    };
    #define LDSA(slot) ((slot)*16384)
    #define LDSB(slot) (32768 + (slot)*16384)

    f32x4 acc[4][2];
    #pragma unroll
    for (int mi = 0; mi < 4; ++mi)
        #pragma unroll
        for (int ni = 0; ni < 2; ++ni)
            acc[mi][ni] = (f32x4){0.f, 0.f, 0.f, 0.f};

    // prologue: stage tile 0 (slot 0): 4 loads/thread outstanding
    STAGE(A + (size_t)bm0 * CC + 0, LDSA(0));
    STAGE(W + (size_t)nn0 * CC + 0, LDSB(0));

    const int lr  = lane & 15;
    const int lg4 = lane >> 4;      // 0..3

    for (int t = 0; t < NT; ++t) {
        const int slot = t & 1;

        // issue next-tile stage into the other slot (overlaps with this tile's compute)
        if (t+1 < NT) {
            STAGE(A + (size_t)bm0 * CC + (t+1)*64, LDSA(slot^1));
            STAGE(W + (size_t)nn0 * CC + (t+1)*64, LDSB(slot^1));
        }
        __builtin_amdgcn_sched_barrier(0);
        if (t < NT-1) asm volatile("s_waitcnt vmcnt(4)" ::: "memory");  // tile t landed
        else          asm volatile("s_waitcnt vmcnt(0)" ::: "memory");
        __builtin_amdgcn_s_barrier();          // all waves' portions of tile t visible

        // 12 swizzled ds_read_b128 (compiler inserts lgkmcnt before MFMA use)
        s16x8 af[4][2], bf[2][2];
        #pragma unroll
        for (int mi = 0; mi < 4; ++mi) {
            const int r = wm*64 + mi*16 + lr;
            #pragma unroll
            for (int ks = 0; ks < 2; ++ks) {
                const int gg = (ks*4 + lg4) ^ (r & 7);
                af[mi][ks] = *(const s16x8*)(LB + LDSA(slot) + r*128 + gg*16);
            }
        }
        #pragma unroll
        for (int ni = 0; ni < 2; ++ni) {
            const int r = wn*32 + ni*16 + lr;
            #pragma unroll
            for (int ks = 0; ks < 2; ++ks) {
                const int gg = (ks*4 + lg4) ^ (r & 7);
                bf[ni][ks] = *(const s16x8*)(LB + LDSB(slot) + r*128 + gg*16);
            }
        }

        __builtin_amdgcn_s_setprio(1);
        #pragma unroll
        for (int mi = 0; mi < 4; ++mi)
            #pragma unroll
            for (int ni = 0; ni < 2; ++ni)
                #pragma unroll
                for (int ks = 0; ks < 2; ++ks)
                    acc[mi][ni] = __builtin_amdgcn_mfma_f32_16x16x32_bf16(
                        af[mi][ks], bf[ni][ks], acc[mi][ni], 0, 0, 0);
        __builtin_amdgcn_s_setprio(0);
        __builtin_amdgcn_sched_barrier(0);     // keep MFMAs (reads' consumers) above barrier
        __builtin_amdgcn_s_barrier();          // all reads of slot done -> safe to overwrite
    }

    // ---- epilogue: scalar stores (R4-style, proven) ----
    #pragma unroll
    for (int mi = 0; mi < 4; ++mi) {
        #pragma unroll
        for (int ni = 0; ni < 2; ++ni) {
            const int coln = nn0 + wn*32 + ni*16 + lr;           // 0..1023 within sel
            const int rb   = bm0 + wm*64 + mi*16 + lg4*4;
            const int h = coln >> 6, d = coln & (DD-1);
            const int b = rb >> 11, t0 = rb & (TT-1);
            u16 bvv[4];
            #pragma unroll
            for (int r = 0; r < 4; ++r) {
                float val = acc[mi][ni][r];
                if (sel != 2) val = fmap(val);
                bvv[r] = bf16r(val);
            }
            if (sel == 0) {
                u16* p = qp + (((size_t)(b*HH + h)) * TT + t0) * DD + d;
                #pragma unroll
                for (int r = 0; r < 4; ++r) p[(size_t)r * DD] = bvv[r];
            } else {
                const int ch = t0 >> 7, tc = t0 & (LCH-1);
                u16* pt = (sel == 1 ? kt : vt)
                        + (((size_t)((b*HH + h)*NCH + ch)) * DD + d) * LCH + tc;
                *(ushort4*)pt = make_ushort4(bvv[0], bvv[1], bvv[2], bvv[3]);
                if (sel == 1) {
                    u16* p = kp + (((size_t)(b*HH + h)) * TT + t0) * DD + d;
                    #pragma unroll
                    for (int r = 0; r < 4; ++r) p[(size_t)r * DD] = bvv[r];
                }
            }
        }
    }
    #undef LDSA
    #undef LDSB
}

// Final GEMM: out[m,n] = sum_k y[m,k]*Wp[n,k] + bp[n]. BM=128, BN=64, dbuf LDS.
__global__ __launch_bounds__(256)
void lca_gemm_out(const u16* __restrict__ A, const u16* __restrict__ W,
                  const float* __restrict__ bias, float* __restrict__ out)
{
    __shared__ short As[2][4096];
    __shared__ short Bs2[2][2048];
    const int tid  = threadIdx.x;
    const int lane = tid & 63;
    const int wid  = tid >> 6;

    const int bid = blockIdx.y * gridDim.x + blockIdx.x;   // 0..511
    const int nb  = (bid & 7) * 64 + (bid >> 3);           // bijective (512%8==0)
    const int bm0 = (nb >> 4) * 128;
    const int bn0 = (nb & 15) * 64;

    const int wm = wid >> 1, wn = wid & 1;

    const int rsA = wid*32 + (lane >> 2);
    const int rsB = wid*16 + (lane >> 2);
    const int kc  = (lane & 3) * 8;

    f32x4 acc[4][2];
    #pragma unroll
    for (int i = 0; i < 4; ++i)
        #pragma unroll
        for (int j = 0; j < 2; ++j)
            acc[i][j] = (f32x4){0.f, 0.f, 0.f, 0.f};

    const int rA = wm*64 + (lane & 15);
    const int rB = wn*32 + (lane & 15);
    const int kk = (lane >> 4) * 8;

    #pragma unroll
    for (int j = 0; j < 2; ++j)
        gload16(A + (size_t)(bm0 + rsA + j*16) * CC + kc, &As[0][wid*1024 + j*512]);
    gload16(W + (size_t)(bn0 + rsB) * CC + kc, &Bs2[0][wid*512]);
    __syncthreads();

    int cur = 0;
    for (int k0 = 0; k0 < CC; k0 += 32) {
        if (k0 + 32 < CC) {
            #pragma unroll
            for (int j = 0; j < 2; ++j)
                gload16(A + (size_t)(bm0 + rsA + j*16) * CC + k0 + 32 + kc, &As[cur^1][wid*1024 + j*512]);
            gload16(W + (size_t)(bn0 + rsB) * CC + k0 + 32 + kc, &Bs2[cur^1][wid*512]);
        }

        s16x8 af[4], bf[2];
        #pragma unroll
        for (int mi = 0; mi < 4; ++mi) af[mi] = *(const s16x8*)(&As[cur][(rA + mi*16)*32 + kk]);
        #pragma unroll
        for (int ni = 0; ni < 2; ++ni) bf[ni] = *(const s16x8*)(&Bs2[cur][(rB + ni*16)*32 + kk]);
        #pragma unroll
        for (int mi = 0; mi < 4; ++mi)
            #pragma unroll
            for (int ni = 0; ni < 2; ++ni)
                acc[mi][ni] = __builtin_amdgcn_mfma_f32_16x16x32_bf16(af[mi], bf[ni], acc[mi][ni], 0, 0, 0);

        __syncthreads();
        cur ^= 1;
    }

    #pragma unroll
    for (int mi = 0; mi < 4; ++mi) {
        #pragma unroll
        for (int ni = 0; ni < 2; ++ni) {
            const int col = bn0 + wn*32 + ni*16 + (lane & 15);
            const int rb  = bm0 + wm*64 + mi*16 + (lane >> 4)*4;
            const float bb = bias[col];
            #pragma unroll
            for (int r = 0; r < 4; ++r)
                out[(size_t)(rb + r) * CC + col] = acc[mi][ni][r] + bb;
        }
    }
}

// Pass 1 (MFMA): per (b,h,chunk): S[d][e] = sum_t kt[d][t]*vt[e][t]; ksum[d]
__global__ __launch_bounds__(256)
void lca_pass1(const u16* __restrict__ kt, const u16* __restrict__ vt,
               float* __restrict__ Sloc, float* __restrict__ ksloc)
{
    const int wid = threadIdx.x >> 6, lane = threadIdx.x & 63;
    const int c = blockIdx.x * 4 + wid, bh = blockIdx.y;
    const u16* kg = kt + ((size_t)bh * NCH + c) * DD * LCH;
    const u16* vg = vt + ((size_t)bh * NCH + c) * DD * LCH;
    const int lr = lane & 15;
    const int lk = (lane >> 4) * 8;

    f32x4 acc[4][4];
    #pragma unroll
    for (int i = 0; i < 4; ++i)
        #pragma unroll
        for (int j = 0; j < 4; ++j)
            acc[i][j] = (f32x4){0.f, 0.f, 0.f, 0.f};

    #pragma unroll
    for (int ks = 0; ks < 4; ++ks) {
        const int k = ks*32 + lk;
        s16x8 af[4], bf[4];
        #pragma unroll
        for (int mi = 0; mi < 4; ++mi) af[mi] = *(const s16x8*)(kg + (size_t)(mi*16 + lr)*LCH + k);
        #pragma unroll
        for (int ni = 0; ni < 4; ++ni) bf[ni] = *(const s16x8*)(vg + (size_t)(ni*16 + lr)*LCH + k);
        #pragma unroll
        for (int mi = 0; mi < 4; ++mi)
            #pragma unroll
            for (int ni = 0; ni < 4; ++ni)
                acc[mi][ni] = __builtin_amdgcn_mfma_f32_16x16x32_bf16(af[mi], bf[ni], acc[mi][ni], 0, 0, 0);
    }

    float* So = Sloc + ((size_t)bh * NCH + c) * (DD*DD);
    #pragma unroll
    for (int mi = 0; mi < 4; ++mi)
        #pragma unroll
        for (int ni = 0; ni < 4; ++ni) {
            const int e = ni*16 + lr;
            #pragma unroll
            for (int r = 0; r < 4; ++r) {
                const int d = mi*16 + (lane >> 4)*4 + r;
                So[(size_t)d * DD + e] = acc[mi][ni][r];
            }
        }

    float s = 0.0f;
    #pragma unroll
    for (int i = 0; i < 16; ++i) {
        s16x8 dv = *(const s16x8*)(kg + (size_t)lane * LCH + i*8);
        #pragma unroll
        for (int j = 0; j < 8; ++j) s += bf2f((u16)dv[j]);
    }
    ksloc[((size_t)bh * NCH + c) * DD + lane] = s;
}

// Pass 2: per (b,h): exclusive scan -> pst (bf16 transposed), pksx, states.
__global__ __launch_bounds__(256)
void lca_pass2(const float* __restrict__ Sloc, const float* __restrict__ ksloc,
               u16* __restrict__ pst, float* __restrict__ pksx,
               float* __restrict__ out)
{
    const int bh = blockIdx.x;
    const int tid = threadIdx.x;
    const int d0 = (tid >> 4) * 4;
    const int e0 = (tid & 15) * 4;

    float run[4][4] = {};
    for (int c = 0; c < NCH; ++c) {
        u16* P = pst + ((size_t)bh * NCH + c) * (DD*DD);
        #pragma unroll
        for (int i = 0; i < 4; ++i)
            #pragma unroll
            for (int j = 0; j < 4; ++j)
                P[(size_t)(e0 + j) * DD + (d0 + i)] = bf16r(run[i][j]);
        const float* S = Sloc + ((size_t)bh * NCH + c) * (DD*DD);
        #pragma unroll
        for (int i = 0; i < 4; ++i) {
            const float4 t4 = *(const float4*)(S + (size_t)(d0 + i) * DD + e0);
            run[i][0] += t4.x; run[i][1] += t4.y; run[i][2] += t4.z; run[i][3] += t4.w;
        }
    }
    float* nkv = out + OUT_OFF_KV + (size_t)bh * (DD*DD);
    #pragma unroll
    for (int i = 0; i < 4; ++i)
        *(float4*)(nkv + (size_t)(d0 + i) * DD + e0) =
            make_float4(run[i][0], run[i][1], run[i][2], run[i][3]);

    if (tid < DD) {
        float r = 0.0f;
        for (int c = 0; c < NCH; ++c) {
            pksx[((size_t)bh * NCH + c) * DD + tid] = r;
            r += ksloc[((size_t)bh * NCH + c) * DD + tid];
        }
        out[OUT_OFF_KSUM + (size_t)bh * DD + tid] = r;
    }
}

// Pass 3 (MFMA): scores = qp@kp^T (causal), den = rowsum + qp.pks + 1e-6,
// y = (qp@P^T + masked_scores@v) / den -> ybf (B,T,C) bf16
__global__ __launch_bounds__(256)
void lca_pass3(const u16* __restrict__ qp, const u16* __restrict__ kp,
               const u16* __restrict__ vt, const u16* __restrict__ pst,
               const float* __restrict__ pksx, u16* __restrict__ ybf)
{
    __shared__ short SA[16384];
    __shared__ short VS[8192];
    __shared__ short PS[4096];
    __shared__ float pks_s[DD];
    __shared__ float den_s[LCH];

    char* SAb = (char*)SA;
    char* VSb = (char*)VS;
    char* PSb = (char*)PS;

    const int c = blockIdx.x, bh = blockIdx.y;
    const int tid = threadIdx.x;
    const int lane = tid & 63, wid = tid >> 6;

    const u16* qg = qp + ((size_t)bh * TT + (size_t)c * LCH) * DD;
    const u16* kg = kp + ((size_t)bh * TT + (size_t)c * LCH) * DD;
    const u16* vg = vt + ((size_t)bh * NCH + c) * DD * LCH;
    const u16* pg = pst + ((size_t)bh * NCH + c) * (DD*DD);

    for (int i = tid; i < 1024; i += 256) {
        const int row = i >> 3, cc = i & 7;
        const s16x8 dv = *(const s16x8*)(qg + (size_t)row*DD + cc*8);
        *(s16x8*)(SAb + ((row*128 + cc*16) ^ ((row & 7) << 4))) = dv;
    }
    for (int i = tid; i < 1024; i += 256) {
        const int row = i >> 3, cc = i & 7;
        const s16x8 dv = *(const s16x8*)(kg + (size_t)row*DD + cc*8);
        *(s16x8*)(SAb + 16384 + ((row*128 + cc*16) ^ ((row & 7) << 4))) = dv;
    }
    for (int i = tid; i < 1024; i += 256) {
        const int row = i >> 4, cc = i & 15;
        const s16x8 dv = *(const s16x8*)(vg + (size_t)row*LCH + cc*8);
        *(s16x8*)(VSb + ((row*256 + cc*16) ^ ((row & 7) << 4))) = dv;
    }
    for (int i = tid; i < 512; i += 256) {
        const int row = i >> 3, cc = i & 7;
        const s16x8 dv = *(const s16x8*)(pg + (size_t)row*DD + cc*8);
        *(s16x8*)(PSb + ((row*128 + cc*16) ^ ((row & 7) << 4))) = dv;
    }
    if (tid < DD) pks_s[tid] = pksx[((size_t)bh * NCH + c) * DD + tid];
    __syncthreads();

    if (tid < LCH) {
        const int t = tid;
        float s = 1e-6f;
        #pragma unroll
        for (int cc = 0; cc < 8; ++cc) {
            const s16x8 dv = *(const s16x8*)(SAb + ((t*128 + cc*16) ^ ((t & 7) << 4)));
            #pragma unroll
            for (int j = 0; j < 8; ++j) s += bf2f((u16)dv[j]) * pks_s[cc*8 + j];
        }
        den_s[t] = s;
    }

    const int wrow0 = wid * 32;
    const int lr = lane & 15;
    const int lg = lane >> 4;
    const int lk = lg * 8;

    f32x4 sacc[2][8];
    #pragma unroll
    for (int mi = 0; mi < 2; ++mi)
        #pragma unroll
        for (int ni = 0; ni < 8; ++ni)
            sacc[mi][ni] = (f32x4){0.f, 0.f, 0.f, 0.f};

    #pragma unroll
    for (int ks = 0; ks < 2; ++ks) {
        const int k2 = (ks*32 + lk) * 2;
        s16x8 af[2];
        #pragma unroll
        for (int mi = 0; mi < 2; ++mi) {
            const int row = wrow0 + mi*16 + lr;
            af[mi] = *(const s16x8*)(SAb + ((row*128 + k2) ^ ((row & 7) << 4)));
        }
        #pragma unroll
        for (int ni = 0; ni < 8; ++ni) {
            const int rowb = ni*16 + lr;
            const s16x8 bf = *(const s16x8*)(SAb + 16384 + ((rowb*128 + k2) ^ ((rowb & 7) << 4)));
            sacc[0][ni] = __builtin_amdgcn_mfma_f32_16x16x32_bf16(af[0], bf, sacc[0][ni], 0, 0, 0);
            sacc[1][ni] = __builtin_amdgcn_mfma_f32_16x16x32_bf16(af[1], bf, sacc[1][ni], 0, 0, 0);
        }
    }

    f32x4 pv[2][4];
    #pragma unroll
    for (int mi = 0; mi < 2; ++mi)
        #pragma unroll
        for (int ni = 0; ni < 4; ++ni)
            pv[mi][ni] = (f32x4){0.f, 0.f, 0.f, 0.f};

    #pragma unroll
    for (int ks = 0; ks < 2; ++ks) {
        const int k2 = (ks*32 + lk) * 2;
        s16x8 af[2];
        #pragma unroll
        for (int mi = 0; mi < 2; ++mi) {
            const int row = wrow0 + mi*16 + lr;
            af[mi] = *(const s16x8*)(SAb + ((row*128 + k2) ^ ((row & 7) << 4)));
        }
        #pragma unroll
        for (int ni = 0; ni < 4; ++ni) {
            const int rowb = ni*16 + lr;
            const s16x8 bf = *(const s16x8*)(PSb + ((rowb*128 + k2) ^ ((rowb & 7) << 4)));
            pv[0][ni] = __builtin_amdgcn_mfma_f32_16x16x32_bf16(af[0], bf, pv[0][ni], 0, 0, 0);
            pv[1][ni] = __builtin_amdgcn_mfma_f32_16x16x32_bf16(af[1], bf, pv[1][ni], 0, 0, 0);
        }
    }
    __syncthreads();

    #pragma unroll
    for (int mi = 0; mi < 2; ++mi) {
        float dr[4] = {0.f, 0.f, 0.f, 0.f};
        #pragma unroll
        for (int ni = 0; ni < 8; ++ni) {
            const int tp = ni*16 + lr;
            #pragma unroll
            for (int r = 0; r < 4; ++r) {
                const int t = wrow0 + mi*16 + lg*4 + r;
                const float v = (tp <= t) ? sacc[mi][ni][r] : 0.f;
                dr[r] += v;
                *(u16*)(SAb + ((t*256 + tp*2) ^ ((t & 7) << 4))) = bf16r(v);
            }
        }
        #pragma unroll
        for (int r = 0; r < 4; ++r) {
            float s = dr[r];
            s += __shfl_xor(s, 1); s += __shfl_xor(s, 2);
            s += __shfl_xor(s, 4); s += __shfl_xor(s, 8);
            if (lr == 0) {
                const int t = wrow0 + mi*16 + lg*4 + r;
                den_s[t] += s;
            }
        }
    }
    __syncthreads();

    #pragma unroll
    for (int ks = 0; ks < 4; ++ks) {
        const int k2 = (ks*32 + lk) * 2;
        s16x8 af[2];
        #pragma unroll
        for (int mi = 0; mi < 2; ++mi) {
            const int row = wrow0 + mi*16 + lr;
            af[mi] = *(const s16x8*)(SAb + ((row*256 + k2) ^ ((row & 7) << 4)));
        }
        #pragma unroll
        for (int ni = 0; ni < 4; ++ni) {
            const int rowb = ni*16 + lr;
            const s16x8 bf = *(const s16x8*)(VSb + ((rowb*256 + k2) ^ ((rowb & 7) << 4)));
            pv[0][ni] = __builtin_amdgcn_mfma_f32_16x16x32_bf16(af[0], bf, pv[0][ni], 0, 0, 0);
            pv[1][ni] = __builtin_amdgcn_mfma_f32_16x16x32_bf16(af[1], bf, pv[1][ni], 0, 0, 0);
        }
    }

    const int b = bh >> 4, h = bh & (HH-1);
    #pragma unroll
    for (int mi = 0; mi < 2; ++mi)
        #pragma unroll
        for (int ni = 0; ni < 4; ++ni) {
            const int e = ni*16 + lr;
            #pragma unroll
            for (int r = 0; r < 4; ++r) {
                const int t = wrow0 + mi*16 + lg*4 + r;
                const float y = pv[mi][ni][r] / den_s[t];
                ybf[((size_t)(b*TT) + (size_t)c*LCH + t) * CC + h*DD + e] = bf16r(y);
            }
        }
}

extern "C" void kernel_launch(void* const* d_in, const int* in_sizes, int n_in,
                              void* d_out, int out_size, void* d_ws, size_t ws_size,
                              hipStream_t stream) {
    const float* x  = (const float*)d_in[0];
    const float* Wq = (const float*)d_in[1];
    const float* Wk = (const float*)d_in[2];
    const float* Wv = (const float*)d_in[3];
    const float* Wp = (const float*)d_in[4];
    const float* bp = (const float*)d_in[5];
    float* out = (float*)d_out;
    char* ws = (char*)d_ws;

    u16*   xbf  = (u16*)(ws + 0);
    u16*   Wbf  = (u16*)(ws + (size_t)8*MB);
    u16*   qp   = (u16*)(ws + (size_t)16*MB);
    u16*   kp   = (u16*)(ws + (size_t)24*MB);
    u16*   kt   = (u16*)(ws + (size_t)32*MB);
    u16*   vt   = (u16*)(ws + (size_t)40*MB);
    u16*   ybf  = (u16*)(ws + (size_t)48*MB);
    float* Sl   = (float*)(ws + (size_t)56*MB);
    float* ksl  = (float*)(ws + (size_t)64*MB);
    float* pksx = (float*)(ws + (size_t)64*MB + 131072);
    u16*   pst  = (u16*)(ws + (size_t)65*MB);

    (void)hipFuncSetAttribute((const void*)lca_gemm_qkv128,
                              hipFuncAttributeMaxDynamicSharedMemorySize, 65536);

    f2bf_all<<<4096, 256, 0, stream>>>(x, Wq, Wk, Wv, Wp, xbf, Wbf);

    lca_gemm_qkv128<<<dim3(3*CC/128, MM/128), 512, 65536, stream>>>(xbf, Wbf, qp, kp, kt, vt);

    lca_pass1<<<dim3(NCH/4, BHH), 256, 0, stream>>>(kt, vt, Sl, ksl);
    lca_pass2<<<BHH, 256, 0, stream>>>(Sl, ksl, pst, pksx, out);
    lca_pass3<<<dim3(NCH, BHH), 256, 0, stream>>>(qp, kp, vt, pst, pksx, ybf);

    lca_gemm_out<<<dim3(CC/64, MM/128), 256, 0, stream>>>(ybf, Wbf + ((size_t)3 << 20), bp, out);
}

// Round 15
// 108.701 us; speedup vs baseline: 1.6641x; 1.0755x over previous
//
#include <hip/hip_runtime.h>
#include <math.h>

#define BB 2
#define TT 2048
#define CC 1024
#define HH 16
#define DD 64
#define MM (BB*TT)
#define LCH 128
#define NCH (TT/LCH)
#define BHH (BB*HH)

#define OUT_OFF_KV   4194304
#define OUT_OFF_KSUM 4325376
#define MB 1048576

typedef unsigned int u32;
typedef unsigned short u16;
typedef __attribute__((ext_vector_type(8))) short s16x8;
typedef __attribute__((ext_vector_type(8))) unsigned short us8;
typedef __attribute__((ext_vector_type(4))) float f32x4;

__device__ __forceinline__ float fmap(float x) {
    return x > 0.0f ? x + 1.0f : expf(x);
}
__device__ __forceinline__ u16 bf16r(float f) {
    u32 u = __float_as_uint(f);
    u += 0x7fffu + ((u >> 16) & 1u);
    return (u16)(u >> 16);
}
__device__ __forceinline__ float bf2f(u16 u) {
    return __uint_as_float(((u32)u) << 16);
}
__device__ __forceinline__ void gload16(const void* g, void* l) {
    __builtin_amdgcn_global_load_lds(
        (const __attribute__((address_space(1))) u32*)g,
        (__attribute__((address_space(3))) u32*)l, 16, 0, 0);
}

// Fused fp32->bf16 cast: x then Wq,Wk,Wv,Wp into xbf and contiguous Wbf.
__global__ __launch_bounds__(256)
void f2bf_all(const float* __restrict__ x,
              const float* __restrict__ Wq, const float* __restrict__ Wk,
              const float* __restrict__ Wv, const float* __restrict__ Wp,
              u16* __restrict__ xbf, u16* __restrict__ wbf)
{
    const int i = blockIdx.x * 256 + threadIdx.x;   // 0 .. 1048575
    const float* src;
    u16* dst;
    int off;
    if (i < 524288) {
        src = x; dst = xbf; off = i;
    } else {
        const int j = i - 524288;
        const int sel = j >> 17;
        off = j & 131071;
        src = (sel == 0) ? Wq : (sel == 1) ? Wk : (sel == 2) ? Wv : Wp;
        dst = wbf + ((size_t)sel << 20);
    }
    const float4 a = ((const float4*)src)[off*2];
    const float4 b = ((const float4*)src)[off*2 + 1];
    us8 p;
    p[0]=bf16r(a.x); p[1]=bf16r(a.y); p[2]=bf16r(a.z); p[3]=bf16r(a.w);
    p[4]=bf16r(b.x); p[5]=bf16r(b.y); p[6]=bf16r(b.z); p[7]=bf16r(b.w);
    ((us8*)dst)[off] = p;
}

// ==================== 128x128 BK=64 QKV GEMM, 8 waves, 2 blocks/CU (R14, proven) ====================
__global__ __launch_bounds__(512, 4)
void lca_gemm_qkv128(const u16* __restrict__ A, const u16* __restrict__ Wall,
                     u16* __restrict__ qp, u16* __restrict__ kp,
                     u16* __restrict__ kt, u16* __restrict__ vt)
{
    extern __shared__ char LB[];    // 65536 bytes: A slots @0,16K; B slots @32K,48K
    const int tid  = threadIdx.x;
    const int lane = tid & 63;
    const int wid  = tid >> 6;      // 0..7
    const int wm   = wid >> 2;      // 0..1
    const int wn   = wid & 3;       // 0..3
    const int bm0  = blockIdx.y * 128;
    const int bn0g = blockIdx.x * 128;
    const int sel  = bn0g >> 10;    // 0,1,2
    const int nn0  = bn0g & (CC-1);
    const u16* W = Wall + ((size_t)sel << 20);
    const int NT = CC / 64;         // 16 K-tiles

    const int srow = (wid << 3) + (lane >> 3);   // 0..63 within sweep
    const int sg   = lane & 7;
    auto STAGE = [&](const u16* G, int ldsbase) {
        #pragma unroll
        for (int j = 0; j < 2; ++j) {
            const int r  = j*64 + srow;
            const int gs = sg ^ (r & 7);
            gload16(G + (size_t)r * CC + gs*8,
                    LB + ldsbase + (size_t)(j*64 + (wid<<3))*128);
        }
    };
    #define LDSA(slot) ((slot)*16384)
    #define LDSB(slot) (32768 + (slot)*16384)

    f32x4 acc[4][2];
    #pragma unroll
    for (int mi = 0; mi < 4; ++mi)
        #pragma unroll
        for (int ni = 0; ni < 2; ++ni)
            acc[mi][ni] = (f32x4){0.f, 0.f, 0.f, 0.f};

    STAGE(A + (size_t)bm0 * CC + 0, LDSA(0));
    STAGE(W + (size_t)nn0 * CC + 0, LDSB(0));

    const int lr  = lane & 15;
    const int lg4 = lane >> 4;      // 0..3

    for (int t = 0; t < NT; ++t) {
        const int slot = t & 1;

        if (t+1 < NT) {
            STAGE(A + (size_t)bm0 * CC + (t+1)*64, LDSA(slot^1));
            STAGE(W + (size_t)nn0 * CC + (t+1)*64, LDSB(slot^1));
        }
        __builtin_amdgcn_sched_barrier(0);
        if (t < NT-1) asm volatile("s_waitcnt vmcnt(4)" ::: "memory");
        else          asm volatile("s_waitcnt vmcnt(0)" ::: "memory");
        __builtin_amdgcn_s_barrier();

        s16x8 af[4][2], bf[2][2];
        #pragma unroll
        for (int mi = 0; mi < 4; ++mi) {
            const int r = wm*64 + mi*16 + lr;
            #pragma unroll
            for (int ks = 0; ks < 2; ++ks) {
                const int gg = (ks*4 + lg4) ^ (r & 7);
                af[mi][ks] = *(const s16x8*)(LB + LDSA(slot) + r*128 + gg*16);
            }
        }
        #pragma unroll
        for (int ni = 0; ni < 2; ++ni) {
            const int r = wn*32 + ni*16 + lr;
            #pragma unroll
            for (int ks = 0; ks < 2; ++ks) {
                const int gg = (ks*4 + lg4) ^ (r & 7);
                bf[ni][ks] = *(const s16x8*)(LB + LDSB(slot) + r*128 + gg*16);
            }
        }

        __builtin_amdgcn_s_setprio(1);
        #pragma unroll
        for (int mi = 0; mi < 4; ++mi)
            #pragma unroll
            for (int ni = 0; ni < 2; ++ni)
                #pragma unroll
                for (int ks = 0; ks < 2; ++ks)
                    acc[mi][ni] = __builtin_amdgcn_mfma_f32_16x16x32_bf16(
                        af[mi][ks], bf[ni][ks], acc[mi][ni], 0, 0, 0);
        __builtin_amdgcn_s_setprio(0);
        __builtin_amdgcn_sched_barrier(0);
        __builtin_amdgcn_s_barrier();
    }

    #pragma unroll
    for (int mi = 0; mi < 4; ++mi) {
        #pragma unroll
        for (int ni = 0; ni < 2; ++ni) {
            const int coln = nn0 + wn*32 + ni*16 + lr;
            const int rb   = bm0 + wm*64 + mi*16 + lg4*4;
            const int h = coln >> 6, d = coln & (DD-1);
            const int b = rb >> 11, t0 = rb & (TT-1);
            u16 bvv[4];
            #pragma unroll
            for (int r = 0; r < 4; ++r) {
                float val = acc[mi][ni][r];
                if (sel != 2) val = fmap(val);
                bvv[r] = bf16r(val);
            }
            if (sel == 0) {
                u16* p = qp + (((size_t)(b*HH + h)) * TT + t0) * DD + d;
                #pragma unroll
                for (int r = 0; r < 4; ++r) p[(size_t)r * DD] = bvv[r];
            } else {
                const int ch = t0 >> 7, tc = t0 & (LCH-1);
                u16* pt = (sel == 1 ? kt : vt)
                        + (((size_t)((b*HH + h)*NCH + ch)) * DD + d) * LCH + tc;
                *(ushort4*)pt = make_ushort4(bvv[0], bvv[1], bvv[2], bvv[3]);
                if (sel == 1) {
                    u16* p = kp + (((size_t)(b*HH + h)) * TT + t0) * DD + d;
                    #pragma unroll
                    for (int r = 0; r < 4; ++r) p[(size_t)r * DD] = bvv[r];
                }
            }
        }
    }
    #undef LDSA
    #undef LDSB
}

// ==================== Final GEMM, qkv128 structure: BM=128 BN=64 BK=64, 4 waves ====================
// out[m,n] = sum_k y[m,k]*Wp[n,k] + bp[n]. LDS 48KB: A 2x16K @0, B 2x8K @32K.
// 4 waves (2M x 2N), wave tile 64x32. Counted vmcnt(6): 6 loads/thread/tile.
__global__ __launch_bounds__(256, 3)
void lca_gemm_out(const u16* __restrict__ A, const u16* __restrict__ W,
                  const float* __restrict__ bias, float* __restrict__ out)
{
    extern __shared__ char LB[];    // 49152 bytes
    const int tid  = threadIdx.x;
    const int lane = tid & 63;
    const int wid  = tid >> 6;      // 0..3
    const int wm   = wid >> 1;      // 0..1
    const int wn   = wid & 1;       // 0..1
    const int bm0  = blockIdx.y * 128;
    const int bn0  = blockIdx.x * 64;
    const int NT = CC / 64;

    const int srw = tid >> 3;       // 0..31
    const int sg  = tid & 7;
    auto STAGE_A = [&](const u16* G, int ldsbase) {
        #pragma unroll
        for (int j = 0; j < 4; ++j) {
            const int r  = j*32 + srw;
            const int gs = sg ^ (r & 7);
            gload16(G + (size_t)r * CC + gs*8,
                    LB + ldsbase + (size_t)j*4096 + (size_t)tid*16);
        }
    };
    auto STAGE_B = [&](const u16* G, int ldsbase) {
        #pragma unroll
        for (int j = 0; j < 2; ++j) {
            const int r  = j*32 + srw;
            const int gs = sg ^ (r & 7);
            gload16(G + (size_t)r * CC + gs*8,
                    LB + ldsbase + (size_t)j*4096 + (size_t)tid*16);
        }
    };
    #define LDSA(slot) ((slot)*16384)
    #define LDSB(slot) (32768 + (slot)*8192)

    f32x4 acc[4][2];
    #pragma unroll
    for (int mi = 0; mi < 4; ++mi)
        #pragma unroll
        for (int ni = 0; ni < 2; ++ni)
            acc[mi][ni] = (f32x4){0.f, 0.f, 0.f, 0.f};

    STAGE_A(A + (size_t)bm0 * CC + 0, LDSA(0));
    STAGE_B(W + (size_t)bn0 * CC + 0, LDSB(0));

    const int lr  = lane & 15;
    const int lg4 = lane >> 4;

    for (int t = 0; t < NT; ++t) {
        const int slot = t & 1;

        if (t+1 < NT) {
            STAGE_A(A + (size_t)bm0 * CC + (t+1)*64, LDSA(slot^1));
            STAGE_B(W + (size_t)bn0 * CC + (t+1)*64, LDSB(slot^1));
        }
        __builtin_amdgcn_sched_barrier(0);
        if (t < NT-1) asm volatile("s_waitcnt vmcnt(6)" ::: "memory");
        else          asm volatile("s_waitcnt vmcnt(0)" ::: "memory");
        __builtin_amdgcn_s_barrier();

        s16x8 af[4][2], bf[2][2];
        #pragma unroll
        for (int mi = 0; mi < 4; ++mi) {
            const int r = wm*64 + mi*16 + lr;
            #pragma unroll
            for (int ks = 0; ks < 2; ++ks) {
                const int gg = (ks*4 + lg4) ^ (r & 7);
                af[mi][ks] = *(const s16x8*)(LB + LDSA(slot) + r*128 + gg*16);
            }
        }
        #pragma unroll
        for (int ni = 0; ni < 2; ++ni) {
            const int r = wn*32 + ni*16 + lr;
            #pragma unroll
            for (int ks = 0; ks < 2; ++ks) {
                const int gg = (ks*4 + lg4) ^ (r & 7);
                bf[ni][ks] = *(const s16x8*)(LB + LDSB(slot) + r*128 + gg*16);
            }
        }

        __builtin_amdgcn_s_setprio(1);
        #pragma unroll
        for (int mi = 0; mi < 4; ++mi)
            #pragma unroll
            for (int ni = 0; ni < 2; ++ni)
                #pragma unroll
                for (int ks = 0; ks < 2; ++ks)
                    acc[mi][ni] = __builtin_amdgcn_mfma_f32_16x16x32_bf16(
                        af[mi][ks], bf[ni][ks], acc[mi][ni], 0, 0, 0);
        __builtin_amdgcn_s_setprio(0);
        __builtin_amdgcn_sched_barrier(0);
        __builtin_amdgcn_s_barrier();
    }

    #pragma unroll
    for (int mi = 0; mi < 4; ++mi) {
        #pragma unroll
        for (int ni = 0; ni < 2; ++ni) {
            const int col = bn0 + wn*32 + ni*16 + lr;
            const int rb  = bm0 + wm*64 + mi*16 + lg4*4;
            const float bb = bias[col];
            #pragma unroll
            for (int r = 0; r < 4; ++r)
                out[(size_t)(rb + r) * CC + col] = acc[mi][ni][r] + bb;
        }
    }
    #undef LDSA
    #undef LDSB
}

// Pass 1 (MFMA): per (b,h,chunk): S[d][e] = sum_t kt[d][t]*vt[e][t]; ksum[d]
__global__ __launch_bounds__(256)
void lca_pass1(const u16* __restrict__ kt, const u16* __restrict__ vt,
               float* __restrict__ Sloc, float* __restrict__ ksloc)
{
    const int wid = threadIdx.x >> 6, lane = threadIdx.x & 63;
    const int c = blockIdx.x * 4 + wid, bh = blockIdx.y;
    const u16* kg = kt + ((size_t)bh * NCH + c) * DD * LCH;
    const u16* vg = vt + ((size_t)bh * NCH + c) * DD * LCH;
    const int lr = lane & 15;
    const int lk = (lane >> 4) * 8;

    f32x4 acc[4][4];
    #pragma unroll
    for (int i = 0; i < 4; ++i)
        #pragma unroll
        for (int j = 0; j < 4; ++j)
            acc[i][j] = (f32x4){0.f, 0.f, 0.f, 0.f};

    #pragma unroll
    for (int ks = 0; ks < 4; ++ks) {
        const int k = ks*32 + lk;
        s16x8 af[4], bf[4];
        #pragma unroll
        for (int mi = 0; mi < 4; ++mi) af[mi] = *(const s16x8*)(kg + (size_t)(mi*16 + lr)*LCH + k);
        #pragma unroll
        for (int ni = 0; ni < 4; ++ni) bf[ni] = *(const s16x8*)(vg + (size_t)(ni*16 + lr)*LCH + k);
        #pragma unroll
        for (int mi = 0; mi < 4; ++mi)
            #pragma unroll
            for (int ni = 0; ni < 4; ++ni)
                acc[mi][ni] = __builtin_amdgcn_mfma_f32_16x16x32_bf16(af[mi], bf[ni], acc[mi][ni], 0, 0, 0);
    }

    float* So = Sloc + ((size_t)bh * NCH + c) * (DD*DD);
    #pragma unroll
    for (int mi = 0; mi < 4; ++mi)
        #pragma unroll
        for (int ni = 0; ni < 4; ++ni) {
            const int e = ni*16 + lr;
            #pragma unroll
            for (int r = 0; r < 4; ++r) {
                const int d = mi*16 + (lane >> 4)*4 + r;
                So[(size_t)d * DD + e] = acc[mi][ni][r];
            }
        }

    float s = 0.0f;
    #pragma unroll
    for (int i = 0; i < 16; ++i) {
        s16x8 dv = *(const s16x8*)(kg + (size_t)lane * LCH + i*8);
        #pragma unroll
        for (int j = 0; j < 8; ++j) s += bf2f((u16)dv[j]);
    }
    ksloc[((size_t)bh * NCH + c) * DD + lane] = s;
}

// Pass 2: per (b,h): exclusive scan -> pst (bf16 transposed), pksx, states.
__global__ __launch_bounds__(256)
void lca_pass2(const float* __restrict__ Sloc, const float* __restrict__ ksloc,
               u16* __restrict__ pst, float* __restrict__ pksx,
               float* __restrict__ out)
{
    const int bh = blockIdx.x;
    const int tid = threadIdx.x;
    const int d0 = (tid >> 4) * 4;
    const int e0 = (tid & 15) * 4;

    float run[4][4] = {};
    for (int c = 0; c < NCH; ++c) {
        u16* P = pst + ((size_t)bh * NCH + c) * (DD*DD);
        #pragma unroll
        for (int i = 0; i < 4; ++i)
            #pragma unroll
            for (int j = 0; j < 4; ++j)
                P[(size_t)(e0 + j) * DD + (d0 + i)] = bf16r(run[i][j]);
        const float* S = Sloc + ((size_t)bh * NCH + c) * (DD*DD);
        #pragma unroll
        for (int i = 0; i < 4; ++i) {
            const float4 t4 = *(const float4*)(S + (size_t)(d0 + i) * DD + e0);
            run[i][0] += t4.x; run[i][1] += t4.y; run[i][2] += t4.z; run[i][3] += t4.w;
        }
    }
    float* nkv = out + OUT_OFF_KV + (size_t)bh * (DD*DD);
    #pragma unroll
    for (int i = 0; i < 4; ++i)
        *(float4*)(nkv + (size_t)(d0 + i) * DD + e0) =
            make_float4(run[i][0], run[i][1], run[i][2], run[i][3]);

    if (tid < DD) {
        float r = 0.0f;
        for (int c = 0; c < NCH; ++c) {
            pksx[((size_t)bh * NCH + c) * DD + tid] = r;
            r += ksloc[((size_t)bh * NCH + c) * DD + tid];
        }
        out[OUT_OFF_KSUM + (size_t)bh * DD + tid] = r;
    }
}

// Pass 3 (MFMA): scores = qp@kp^T (causal), den = rowsum + qp.pks + 1e-6,
// y = (qp@P^T + masked_scores@v) / den -> ybf (B,T,C) bf16
__global__ __launch_bounds__(256)
void lca_pass3(const u16* __restrict__ qp, const u16* __restrict__ kp,
               const u16* __restrict__ vt, const u16* __restrict__ pst,
               const float* __restrict__ pksx, u16* __restrict__ ybf)
{
    __shared__ short SA[16384];
    __shared__ short VS[8192];
    __shared__ short PS[4096];
    __shared__ float pks_s[DD];
    __shared__ float den_s[LCH];

    char* SAb = (char*)SA;
    char* VSb = (char*)VS;
    char* PSb = (char*)PS;

    const int c = blockIdx.x, bh = blockIdx.y;
    const int tid = threadIdx.x;
    const int lane = tid & 63, wid = tid >> 6;

    const u16* qg = qp + ((size_t)bh * TT + (size_t)c * LCH) * DD;
    const u16* kg = kp + ((size_t)bh * TT + (size_t)c * LCH) * DD;
    const u16* vg = vt + ((size_t)bh * NCH + c) * DD * LCH;
    const u16* pg = pst + ((size_t)bh * NCH + c) * (DD*DD);

    for (int i = tid; i < 1024; i += 256) {
        const int row = i >> 3, cc = i & 7;
        const s16x8 dv = *(const s16x8*)(qg + (size_t)row*DD + cc*8);
        *(s16x8*)(SAb + ((row*128 + cc*16) ^ ((row & 7) << 4))) = dv;
    }
    for (int i = tid; i < 1024; i += 256) {
        const int row = i >> 3, cc = i & 7;
        const s16x8 dv = *(const s16x8*)(kg + (size_t)row*DD + cc*8);
        *(s16x8*)(SAb + 16384 + ((row*128 + cc*16) ^ ((row & 7) << 4))) = dv;
    }
    for (int i = tid; i < 1024; i += 256) {
        const int row = i >> 4, cc = i & 15;
        const s16x8 dv = *(const s16x8*)(vg + (size_t)row*LCH + cc*8);
        *(s16x8*)(VSb + ((row*256 + cc*16) ^ ((row & 7) << 4))) = dv;
    }
    for (int i = tid; i < 512; i += 256) {
        const int row = i >> 3, cc = i & 7;
        const s16x8 dv = *(const s16x8*)(pg + (size_t)row*DD + cc*8);
        *(s16x8*)(PSb + ((row*128 + cc*16) ^ ((row & 7) << 4))) = dv;
    }
    if (tid < DD) pks_s[tid] = pksx[((size_t)bh * NCH + c) * DD + tid];
    __syncthreads();

    if (tid < LCH) {
        const int t = tid;
        float s = 1e-6f;
        #pragma unroll
        for (int cc = 0; cc < 8; ++cc) {
            const s16x8 dv = *(const s16x8*)(SAb + ((t*128 + cc*16) ^ ((t & 7) << 4)));
            #pragma unroll
            for (int j = 0; j < 8; ++j) s += bf2f((u16)dv[j]) * pks_s[cc*8 + j];
        }
        den_s[t] = s;
    }

    const int wrow0 = wid * 32;
    const int lr = lane & 15;
    const int lg = lane >> 4;
    const int lk = lg * 8;

    f32x4 sacc[2][8];
    #pragma unroll
    for (int mi = 0; mi < 2; ++mi)
        #pragma unroll
        for (int ni = 0; ni < 8; ++ni)
            sacc[mi][ni] = (f32x4){0.f, 0.f, 0.f, 0.f};

    #pragma unroll
    for (int ks = 0; ks < 2; ++ks) {
        const int k2 = (ks*32 + lk) * 2;
        s16x8 af[2];
        #pragma unroll
        for (int mi = 0; mi < 2; ++mi) {
            const int row = wrow0 + mi*16 + lr;
            af[mi] = *(const s16x8*)(SAb + ((row*128 + k2) ^ ((row & 7) << 4)));
        }
        #pragma unroll
        for (int ni = 0; ni < 8; ++ni) {
            const int rowb = ni*16 + lr;
            const s16x8 bf = *(const s16x8*)(SAb + 16384 + ((rowb*128 + k2) ^ ((rowb & 7) << 4)));
            sacc[0][ni] = __builtin_amdgcn_mfma_f32_16x16x32_bf16(af[0], bf, sacc[0][ni], 0, 0, 0);
            sacc[1][ni] = __builtin_amdgcn_mfma_f32_16x16x32_bf16(af[1], bf, sacc[1][ni], 0, 0, 0);
        }
    }

    f32x4 pv[2][4];
    #pragma unroll
    for (int mi = 0; mi < 2; ++mi)
        #pragma unroll
        for (int ni = 0; ni < 4; ++ni)
            pv[mi][ni] = (f32x4){0.f, 0.f, 0.f, 0.f};

    #pragma unroll
    for (int ks = 0; ks < 2; ++ks) {
        const int k2 = (ks*32 + lk) * 2;
        s16x8 af[2];
        #pragma unroll
        for (int mi = 0; mi < 2; ++mi) {
            const int row = wrow0 + mi*16 + lr;
            af[mi] = *(const s16x8*)(SAb + ((row*128 + k2) ^ ((row & 7) << 4)));
        }
        #pragma unroll
        for (int ni = 0; ni < 4; ++ni) {
            const int rowb = ni*16 + lr;
            const s16x8 bf = *(const s16x8*)(PSb + ((rowb*128 + k2) ^ ((rowb & 7) << 4)));
            pv[0][ni] = __builtin_amdgcn_mfma_f32_16x16x32_bf16(af[0], bf, pv[0][ni], 0, 0, 0);
            pv[1][ni] = __builtin_amdgcn_mfma_f32_16x16x32_bf16(af[1], bf, pv[1][ni], 0, 0, 0);
        }
    }
    __syncthreads();

    #pragma unroll
    for (int mi = 0; mi < 2; ++mi) {
        float dr[4] = {0.f, 0.f, 0.f, 0.f};
        #pragma unroll
        for (int ni = 0; ni < 8; ++ni) {
            const int tp = ni*16 + lr;
            #pragma unroll
            for (int r = 0; r < 4; ++r) {
                const int t = wrow0 + mi*16 + lg*4 + r;
                const float v = (tp <= t) ? sacc[mi][ni][r] : 0.f;
                dr[r] += v;
                *(u16*)(SAb + ((t*256 + tp*2) ^ ((t & 7) << 4))) = bf16r(v);
            }
        }
        #pragma unroll
        for (int r = 0; r < 4; ++r) {
            float s = dr[r];
            s += __shfl_xor(s, 1); s += __shfl_xor(s, 2);
            s += __shfl_xor(s, 4); s += __shfl_xor(s, 8);
            if (lr == 0) {
                const int t = wrow0 + mi*16 + lg*4 + r;
                den_s[t] += s;
            }
        }
    }
    __syncthreads();

    #pragma unroll
    for (int ks = 0; ks < 4; ++ks) {
        const int k2 = (ks*32 + lk) * 2;
        s16x8 af[2];
        #pragma unroll
        for (int mi = 0; mi < 2; ++mi) {
            const int row = wrow0 + mi*16 + lr;
            af[mi] = *(const s16x8*)(SAb + ((row*256 + k2) ^ ((row & 7) << 4)));
        }
        #pragma unroll
        for (int ni = 0; ni < 4; ++ni) {
            const int rowb = ni*16 + lr;
            const s16x8 bf = *(const s16x8*)(VSb + ((rowb*256 + k2) ^ ((rowb & 7) << 4)));
            pv[0][ni] = __builtin_amdgcn_mfma_f32_16x16x32_bf16(af[0], bf, pv[0][ni], 0, 0, 0);
            pv[1][ni] = __builtin_amdgcn_mfma_f32_16x16x32_bf16(af[1], bf, pv[1][ni], 0, 0, 0);
        }
    }

    const int b = bh >> 4, h = bh & (HH-1);
    #pragma unroll
    for (int mi = 0; mi < 2; ++mi)
        #pragma unroll
        for (int ni = 0; ni < 4; ++ni) {
            const int e = ni*16 + lr;
            #pragma unroll
            for (int r = 0; r < 4; ++r) {
                const int t = wrow0 + mi*16 + lg*4 + r;
                const float y = pv[mi][ni][r] / den_s[t];
                ybf[((size_t)(b*TT) + (size_t)c*LCH + t) * CC + h*DD + e] = bf16r(y);
            }
        }
}

extern "C" void kernel_launch(void* const* d_in, const int* in_sizes, int n_in,
                              void* d_out, int out_size, void* d_ws, size_t ws_size,
                              hipStream_t stream) {
    const float* x  = (const float*)d_in[0];
    const float* Wq = (const float*)d_in[1];
    const float* Wk = (const float*)d_in[2];
    const float* Wv = (const float*)d_in[3];
    const float* Wp = (const float*)d_in[4];
    const float* bp = (const float*)d_in[5];
    float* out = (float*)d_out;
    char* ws = (char*)d_ws;

    u16*   xbf  = (u16*)(ws + 0);
    u16*   Wbf  = (u16*)(ws + (size_t)8*MB);
    u16*   qp   = (u16*)(ws + (size_t)16*MB);
    u16*   kp   = (u16*)(ws + (size_t)24*MB);
    u16*   kt   = (u16*)(ws + (size_t)32*MB);
    u16*   vt   = (u16*)(ws + (size_t)40*MB);
    u16*   ybf  = (u16*)(ws + (size_t)48*MB);
    float* Sl   = (float*)(ws + (size_t)56*MB);
    float* ksl  = (float*)(ws + (size_t)64*MB);
    float* pksx = (float*)(ws + (size_t)64*MB + 131072);
    u16*   pst  = (u16*)(ws + (size_t)65*MB);

    (void)hipFuncSetAttribute((const void*)lca_gemm_qkv128,
                              hipFuncAttributeMaxDynamicSharedMemorySize, 65536);
    (void)hipFuncSetAttribute((const void*)lca_gemm_out,
                              hipFuncAttributeMaxDynamicSharedMemorySize, 49152);

    f2bf_all<<<4096, 256, 0, stream>>>(x, Wq, Wk, Wv, Wp, xbf, Wbf);

    lca_gemm_qkv128<<<dim3(3*CC/128, MM/128), 512, 65536, stream>>>(xbf, Wbf, qp, kp, kt, vt);

    lca_pass1<<<dim3(NCH/4, BHH), 256, 0, stream>>>(kt, vt, Sl, ksl);
    lca_pass2<<<BHH, 256, 0, stream>>>(Sl, ksl, pst, pksx, out);
    lca_pass3<<<dim3(NCH, BHH), 256, 0, stream>>>(qp, kp, vt, pst, pksx, ybf);

    lca_gemm_out<<<dim3(CC/64, MM/128), 256, 49152, stream>>>(ybf, Wbf + ((size_t)3 << 20), bp, out);
}